// Round 6
// baseline (594.502 us; speedup 1.0000x reference)
//
#include <hip/hip_runtime.h>
#include <stdint.h>

#define DIMSZ 2048
#define HD 128
#define NH 16
#define BATCH 2
#define SEQ 2048
#define MROWS (BATCH*SEQ)   // 4096
#define FFDIM (4*DIMSZ)     // 8192
#define NQKV (DIMSZ + 2*HD) // 2304

typedef float f32x4 __attribute__((ext_vector_type(4)));
typedef __bf16 bf16x8 __attribute__((ext_vector_type(8)));
typedef __bf16 bf16_t;

__device__ __forceinline__ void async16(const void* g, void* l) {
  __builtin_amdgcn_global_load_lds(
      (const __attribute__((address_space(1))) void*)(uintptr_t)g,
      (__attribute__((address_space(3))) void*)(uint32_t)(uintptr_t)l,
      16, 0, 0);
}

__device__ __forceinline__ float gelu_f(float x) {
  return 0.5f * x * (1.0f + erff(x * 0.70710678118654752f));
}

__device__ __forceinline__ void hard_barrier() {
  asm volatile("" ::: "memory");
  __builtin_amdgcn_s_barrier();
  asm volatile("" ::: "memory");
}

// ---------------- transpose f32 (R x C) -> bf16 (C x R) ----------------
__global__ __launch_bounds__(256)
void k_transpose_f32_bf16(const float* __restrict__ src, bf16_t* __restrict__ dst,
                          int R, int C) {
  __shared__ float tile[32][33];
  int c0 = blockIdx.x * 32, r0 = blockIdx.y * 32;
  int tx = threadIdx.x & 31, ty = threadIdx.x >> 5;
#pragma unroll
  for (int i = 0; i < 32; i += 8)
    tile[ty + i][tx] = src[(size_t)(r0 + ty + i) * C + (c0 + tx)];
  __syncthreads();
#pragma unroll
  for (int i = 0; i < 32; i += 8)
    dst[(size_t)(c0 + ty + i) * R + (r0 + tx)] = (bf16_t)tile[tx][ty + i];
}

// ---------------- transpose v bf16 [B*T][128] -> vt [B][128][T] ----------------
__global__ __launch_bounds__(256)
void k_transpose_v(const bf16_t* __restrict__ v, bf16_t* __restrict__ vt) {
  __shared__ bf16_t tile[32][33];
  int b = blockIdx.z;
  int t0 = blockIdx.x * 32, d0 = blockIdx.y * 32;
  int tx = threadIdx.x & 31, ty = threadIdx.x >> 5;
#pragma unroll
  for (int i = 0; i < 32; i += 8)
    tile[ty + i][tx] = v[((size_t)(b * SEQ + t0 + ty + i)) * HD + d0 + tx];
  __syncthreads();
#pragma unroll
  for (int i = 0; i < 32; i += 8)
    vt[((size_t)(b * HD + d0 + ty + i)) * SEQ + t0 + tx] = tile[tx][ty + i];
}

// ---------------- layernorm f32 -> bf16 ----------------
__global__ __launch_bounds__(256)
void k_layernorm(const float* __restrict__ x, const float* __restrict__ g,
                 const float* __restrict__ bb, bf16_t* __restrict__ out) {
  int row = blockIdx.x;
  const float* xr = x + (size_t)row * DIMSZ;
  int t = threadIdx.x;
  float vals[8];
  float s = 0.f, s2 = 0.f;
#pragma unroll
  for (int i = 0; i < 8; ++i) {
    float v = xr[t + i * 256];
    vals[i] = v; s += v; s2 += v * v;
  }
#pragma unroll
  for (int o = 1; o < 64; o <<= 1) { s += __shfl_xor(s, o); s2 += __shfl_xor(s2, o); }
  __shared__ float red[8];
  if ((t & 63) == 0) { red[t >> 6] = s; red[4 + (t >> 6)] = s2; }
  __syncthreads();
  s = red[0] + red[1] + red[2] + red[3];
  s2 = red[4] + red[5] + red[6] + red[7];
  float mu = s * (1.0f / DIMSZ);
  float rstd = rsqrtf(s2 * (1.0f / DIMSZ) - mu * mu + 1e-5f);
  bf16_t* orow = out + (size_t)row * DIMSZ;
#pragma unroll
  for (int i = 0; i < 8; ++i) {
    int c = t + i * 256;
    orow[c] = (bf16_t)((vals[i] - mu) * rstd * g[c] + bb[c]);
  }
}

// =====================================================================
// 8-phase 256xBN GEMM main loop (T2+T3+T4+T5 stack, plain HIP).
// FN = n-frags per wave (4 -> BN=256, 2 -> BN=128). BK=64, 512 threads,
// 8 waves (2M x 4N), per-wave output 128 x FN*16.
// LDS: A [2buf][2half][128][64], B [2buf][BH half][128][64], BH=FN/2.
// XOR swizzle: phys col = logical col ^ ((row&7)<<3); applied on the
// global SOURCE address of global_load_lds (dest linear) and on ds_read.
// CORRECTNESS INVARIANT: all ds_reads of a buffer happen in phases BEFORE
// any stage that overwrites it is issued (B of tile c is read ENTIRELY in
// P1/P5, before P2/P6 stage into it). Do not split ldb across phases.
//   vmcnt(6) [BH=2] / vmcnt(4) [BH=1] at P4 and P8 only; vmcnt(0) at P4
//   of the last iteration. Raw s_barrier x2 per phase; setprio around MFMA.
// =====================================================================
template <int FN>
__device__ __forceinline__ void gemm8_loop(
    const bf16_t* __restrict__ A, const bf16_t* __restrict__ BT, int K,
    int bm, int bn, f32x4 (&acc)[8][FN], bf16_t* sh) {
  constexpr int BH = FN >> 1;
  constexpr int BN = FN * 64;
  const int tid = threadIdx.x;
  const int lane = tid & 63, lr = lane & 15, lg = lane >> 4;
  const int wave = tid >> 6, wm = wave >> 2, wn = wave & 3;
  bf16_t* const Ab0 = sh;            // [(c*2+h)*8192]
  bf16_t* const Bb0 = sh + 32768;    // [(c*BH+h)*8192]
  const bf16_t* const Ag = A + (size_t)bm * 256 * K;
  const bf16_t* const Bg = BT + (size_t)bn * BN * K;

  auto stage = [&](const bf16_t* gbase, bf16_t* lbase, int h, int t) {
#pragma unroll
    for (int j = 0; j < 2; ++j) {
      int flat = (tid + j * 512) * 8;
      int r = flat >> 6, kp = flat & 63;
      int ks = kp ^ ((r & 7) << 3);
      async16(gbase + (size_t)(h * 128 + r) * K + t * 64 + ks, lbase + flat);
    }
  };
  auto stA = [&](int c, int h, int t) { stage(Ag, Ab0 + (c * 2 + h) * 8192, h, t); };
  auto stB = [&](int c, int h, int t) { stage(Bg, Bb0 + (c * BH + h) * 8192, h, t); };

  const int xsw = (lr & 7) << 3;
  bf16x8 a_[8], b_[FN][2];
  auto lda = [&](int c, int kk) {
    const bf16_t* base = Ab0 + (c * 2 + wm) * 8192;
#pragma unroll
    for (int mf = 0; mf < 8; ++mf)
      a_[mf] = *(const bf16x8*)(base + (mf * 16 + lr) * 64 + ((kk + lg * 8) ^ xsw));
  };
  auto ldb = [&](int c) {
#pragma unroll
    for (int nf = 0; nf < FN; ++nf) {
      int row = wn * (FN * 16) + nf * 16 + lr;
      const bf16_t* base =
          Bb0 + (c * BH + (BH == 2 ? (row >> 7) : 0)) * 8192 + (row & 127) * 64;
#pragma unroll
      for (int kx = 0; kx < 2; ++kx)
        b_[nf][kx] = *(const bf16x8*)(base + ((kx * 32 + lg * 8) ^ xsw));
    }
  };

#define LGKM0 asm volatile("s_waitcnt lgkmcnt(0)" ::: "memory");
#define VMC_STEADY                                                   \
  if (BH == 2) { asm volatile("s_waitcnt vmcnt(6)" ::: "memory"); }  \
  else         { asm volatile("s_waitcnt vmcnt(4)" ::: "memory"); }
#define MFMA_HALF(M0, KX)                                            \
  __builtin_amdgcn_s_setprio(1);                                     \
  _Pragma("unroll")                                                  \
  for (int mf = 0; mf < 4; ++mf)                                     \
    _Pragma("unroll")                                                \
    for (int nf = 0; nf < FN; ++nf)                                  \
      acc[(M0) + mf][nf] = __builtin_amdgcn_mfma_f32_16x16x32_bf16(  \
          a_[(M0) + mf], b_[nf][KX], acc[(M0) + mf][nf], 0, 0, 0);   \
  __builtin_amdgcn_s_setprio(0);

  const int nit = K >> 7;  // 2 K-tiles (of 64) per iteration

  // ---- prologue: T0 all halves, then T1.{B0[,B1],A0} ----
  stA(0, 0, 0); stA(0, 1, 0);
  stB(0, 0, 0); if (BH == 2) stB(0, 1, 0);
  stB(1, 0, 1); if (BH == 2) stB(1, 1, 1);
  stA(1, 0, 1);
  VMC_STEADY;
  hard_barrier();

  for (int i = 0; i < nit; ++i) {
    const int t1 = 2 * i + 1, t2 = 2 * i + 2, t3 = 2 * i + 3;
    const bool g2 = (i < nit - 1);
    // ---- P1 ----
    lda(0, 0); ldb(0);
    stA(1, 1, t1);
    hard_barrier(); LGKM0;
    MFMA_HALF(0, 0)
    hard_barrier();
    // ---- P2 ----
    if (g2) stB(0, 0, t2);
    hard_barrier();
    MFMA_HALF(4, 0)
    hard_barrier();
    // ---- P3 ----
    lda(0, 32);
    if (g2 && BH == 2) stB(0, 1, t2);
    hard_barrier(); LGKM0;
    MFMA_HALF(0, 1)
    hard_barrier();
    // ---- P4 ----
    if (g2) stA(0, 0, t2);
    if (i == nit - 1) { asm volatile("s_waitcnt vmcnt(0)" ::: "memory"); }
    else { VMC_STEADY; }
    hard_barrier();
    MFMA_HALF(4, 1)
    hard_barrier();
    // ---- P5 ----
    lda(1, 0); ldb(1);
    if (g2) stA(0, 1, t2);
    hard_barrier(); LGKM0;
    MFMA_HALF(0, 0)
    hard_barrier();
    // ---- P6 ----
    if (g2) stB(1, 0, t3);
    hard_barrier();
    MFMA_HALF(4, 0)
    hard_barrier();
    // ---- P7 ----
    lda(1, 32);
    if (g2 && BH == 2) stB(1, 1, t3);
    hard_barrier(); LGKM0;
    MFMA_HALF(0, 1)
    hard_barrier();
    // ---- P8 ----
    if (g2) {
      stA(1, 0, t3);
      VMC_STEADY;
    }
    hard_barrier();
    MFMA_HALF(4, 1)
    hard_barrier();
  }
#undef LGKM0
#undef VMC_STEADY
#undef MFMA_HALF
}

// ---------------- generic 8-phase GEMM kernel ----------------
// EPI bits: 1 = exact GELU, 2 = add residual f32, 4 = write f32, 8 = write bf16
template <int FN, int EPI>
__global__ __launch_bounds__(512, 1)
void k_gemm8(const bf16_t* __restrict__ A, const bf16_t* __restrict__ BT,
             const float* __restrict__ bias, const float* __restrict__ res,
             float* __restrict__ outF, bf16_t* __restrict__ outB, int N, int K) {
  extern __shared__ __align__(16) bf16_t sh8[];
  constexpr int BN = FN * 64;
  int nt = N / BN;
  int bm = blockIdx.x / nt, bn = blockIdx.x % nt;
  f32x4 acc[8][FN] = {};
  gemm8_loop<FN>(A, BT, K, bm, bn, acc, sh8);
  int tid = threadIdx.x, wave = tid >> 6, lane = tid & 63, lr = lane & 15, lg = lane >> 4;
  int wm = wave >> 2, wn = wave & 3;
  int row0 = bm * 256 + wm * 128 + lg * 4;
  int col0 = bn * BN + wn * (FN * 16) + lr;
#pragma unroll
  for (int nf = 0; nf < FN; ++nf) {
    int c = col0 + nf * 16;
    float bi = bias[c];
#pragma unroll
    for (int mf = 0; mf < 8; ++mf) {
#pragma unroll
      for (int j = 0; j < 4; ++j) {
        int r = row0 + mf * 16 + j;
        size_t idx = (size_t)r * N + c;
        float v = acc[mf][nf][j] + bi;
        if (EPI & 1) v = gelu_f(v);
        if (EPI & 2) v += res[idx];
        if (EPI & 4) outF[idx] = v;
        if (EPI & 8) outB[idx] = (bf16_t)v;
      }
    }
  }
}

// ---------------- fused QKV 8-phase GEMM: N = 2304 (2048 q|128 k|128 v) ------
__global__ __launch_bounds__(512, 1)
void k_gemm8_qkv(const bf16_t* __restrict__ A, const bf16_t* __restrict__ BT,
                 const float* __restrict__ bq, const float* __restrict__ bk,
                 const float* __restrict__ bv,
                 bf16_t* __restrict__ qb, float* __restrict__ outk,
                 float* __restrict__ outv, bf16_t* __restrict__ kbf,
                 bf16_t* __restrict__ vbf, int K) {
  extern __shared__ __align__(16) bf16_t sh8[];
  const int nt = NQKV / 256;  // 9
  int bm = blockIdx.x / nt, bn = blockIdx.x % nt;
  f32x4 acc[8][4] = {};
  gemm8_loop<4>(A, BT, K, bm, bn, acc, sh8);
  int tid = threadIdx.x, wave = tid >> 6, lane = tid & 63, lr = lane & 15, lg = lane >> 4;
  int wm = wave >> 2, wn = wave & 3;
  int row0 = bm * 256 + wm * 128 + lg * 4;
  int col0 = bn * 256 + wn * 64 + lr;
#pragma unroll
  for (int nf = 0; nf < 4; ++nf) {
    int c = col0 + nf * 16;
    float bi = (c < 2048) ? bq[c] : (c < 2176 ? bk[c - 2048] : bv[c - 2176]);
#pragma unroll
    for (int mf = 0; mf < 8; ++mf) {
#pragma unroll
      for (int j = 0; j < 4; ++j) {
        int r = row0 + mf * 16 + j;
        float v = acc[mf][nf][j] + bi;
        if (c < 2048) {
          qb[(size_t)r * DIMSZ + c] = (bf16_t)v;
        } else if (c < 2176) {
          int cc = c - 2048;
          outk[(size_t)r * HD + cc] = v;
          kbf[(size_t)r * HD + cc] = (bf16_t)v;
        } else {
          int cc = c - 2176;
          outv[(size_t)r * HD + cc] = v;
          vbf[(size_t)r * HD + cc] = (bf16_t)v;
        }
      }
    }
  }
}

// ---------------- causal flash attention (MQA) ----------------
// Block = 4 waves sharing one 64-row q-tile (16 rows/wave). Block p handles
// q-tiles {p, 31-p} sequentially -> uniform 33 KV-tiles/block. K [64][128] and
// V^T [128][64] staged in LDS (double-buffered) via global_load_lds with
// chunk-XOR swizzle (pre-swizzled global source + XOR on ds_read). 2-phase
// pipeline: STAGE(t+1) issued before compute(t), one barrier per tile.
__global__ __launch_bounds__(256, 2)
void k_attn(const bf16_t* __restrict__ q, const bf16_t* __restrict__ k,
            const bf16_t* __restrict__ vt, bf16_t* __restrict__ ctx) {
  __shared__ __align__(16) bf16_t Ks[2][64 * 128];
  __shared__ __align__(16) bf16_t Vs[2][128 * 64];
  __shared__ bf16_t Pw[4][16][72];
  int pp = blockIdx.x, h = blockIdx.y, b = blockIdx.z;
  int tid = threadIdx.x, wave = tid >> 6, lane = tid & 63, lr = lane & 15, lg = lane >> 4;
  const bf16_t* kb = k + (size_t)b * SEQ * HD;
  const bf16_t* vb = vt + (size_t)b * HD * SEQ;

#define STAGE_TILE(buf, s0_)                                                      \
  {                                                                               \
    _Pragma("unroll")                                                             \
    for (int i = 0; i < 4; ++i) {                                                 \
      int flat = (i * 256 + tid) * 8;                                             \
      int kr = flat >> 7, kc = flat & 127;                                        \
      int ksrc = (((kc >> 3) ^ (kr & 7)) << 3) | (kc & 7);                        \
      async16(kb + (size_t)((s0_) + kr) * HD + ksrc, (void*)(Ks[buf] + flat));    \
      int vr = flat >> 6, vc = flat & 63;                                         \
      int vsrc = (((vc >> 3) ^ (vr & 7)) << 3) | (vc & 7);                        \
      async16(vb + (size_t)vr * SEQ + (s0_) + vsrc, (void*)(Vs[buf] + flat));     \
    }                                                                             \
  }

  for (int half = 0; half < 2; ++half) {
    int qt = half ? (31 - pp) : pp;
    int q0 = qt * 64;
    int qw = q0 + wave * 16;
    const bf16_t* qbase = q + ((size_t)(b * SEQ + qw + lr)) * DIMSZ + h * HD;
    bf16x8 qf[4];
#pragma unroll
    for (int kk = 0; kk < 4; ++kk) qf[kk] = *(const bf16x8*)(qbase + kk * 32 + lg * 8);
    f32x4 o[8] = {};
    float m_[4], l_[4];
#pragma unroll
    for (int j = 0; j < 4; ++j) { m_[j] = -3.0e38f; l_[j] = 0.f; }
    int qglob0 = qw + lg * 4;
    int ntiles = qt + 1;

    STAGE_TILE(0, 0)
    __syncthreads();
    for (int t = 0; t < ntiles; ++t) {
      int cur = t & 1;
      if (t + 1 < ntiles) STAGE_TILE(cur ^ 1, (t + 1) * 64)
      int s0 = t * 64;
      const bf16_t* Kc = Ks[cur];
      const bf16_t* Vc = Vs[cur];
      f32x4 sf[4] = {};
#pragma unroll
      for (int nf = 0; nf < 4; ++nf) {
        int R = nf * 16 + lr;
#pragma unroll
        for (int kk = 0; kk < 4; ++kk)
          sf[nf] = __builtin_amdgcn_mfma_f32_16x16x32_bf16(
              qf[kk],
              *(const bf16x8*)(Kc + R * 128 + (((kk * 4 + lg) ^ (R & 7)) << 3)),
              sf[nf], 0, 0, 0);
      }
#pragma unroll
      for (int nf = 0; nf < 4; ++nf) {
        int col = s0 + nf * 16 + lr;
#pragma unroll
        for (int j = 0; j < 4; ++j) {
          float v = sf[nf][j] * 0.088388347648318447f;
          sf[nf][j] = (col <= qglob0 + j) ? v : -3.0e38f;
        }
      }
      float mx[4];
#pragma unroll
      for (int j = 0; j < 4; ++j)
        mx[j] = fmaxf(fmaxf(sf[0][j], sf[1][j]), fmaxf(sf[2][j], sf[3][j]));
#pragma unroll
      for (int o_ = 1; o_ < 16; o_ <<= 1)
#pragma unroll
        for (int j = 0; j < 4; ++j) mx[j] = fmaxf(mx[j], __shfl_xor(mx[j], o_));
      float fsc[4], mn[4];
#pragma unroll
      for (int j = 0; j < 4; ++j) {
        mn[j] = fmaxf(m_[j], mx[j]);
        fsc[j] = __expf(m_[j] - mn[j]);
        m_[j] = mn[j];
      }
      float ps[4] = {0.f, 0.f, 0.f, 0.f};
#pragma unroll
      for (int nf = 0; nf < 4; ++nf)
#pragma unroll
        for (int j = 0; j < 4; ++j) {
          float pv = __expf(sf[nf][j] - mn[j]);
          ps[j] += pv;
          Pw[wave][lg * 4 + j][nf * 16 + lr] = (bf16_t)pv;
        }
#pragma unroll
      for (int o_ = 1; o_ < 16; o_ <<= 1)
#pragma unroll
        for (int j = 0; j < 4; ++j) ps[j] += __shfl_xor(ps[j], o_);
#pragma unroll
      for (int j = 0; j < 4; ++j) l_[j] = l_[j] * fsc[j] + ps[j];
#pragma unroll
      for (int df = 0; df < 8; ++df)
#pragma unroll
        for (int j = 0; j < 4; ++j) o[df][j] *= fsc[j];
      asm volatile("" ::: "memory");
      bf16x8 pa[2];
#pragma unroll
      for (int kk = 0; kk < 2; ++kk)
        pa[kk] = *(const bf16x8*)(&Pw[wave][lr][kk * 32 + lg * 8]);
#pragma unroll
      for (int df = 0; df < 8; ++df) {
        int R = df * 16 + lr;
#pragma unroll
        for (int kk = 0; kk < 2; ++kk)
          o[df] = __builtin_amdgcn_mfma_f32_16x16x32_bf16(
              pa[kk],
              *(const bf16x8*)(Vc + R * 64 + (((kk * 4 + lg) ^ (R & 7)) << 3)),
              o[df], 0, 0, 0);
      }
      __syncthreads();
    }
    bf16_t* cb = ctx + ((size_t)(b * SEQ + qw)) * DIMSZ + h * HD;
#pragma unroll
    for (int df = 0; df < 8; ++df)
#pragma unroll
      for (int j = 0; j < 4; ++j)
        cb[(size_t)(lg * 4 + j) * DIMSZ + df * 16 + lr] = (bf16_t)(o[df][j] / l_[j]);
  }
#undef STAGE_TILE
}

extern "C" void kernel_launch(void* const* d_in, const int* in_sizes, int n_in,
                              void* d_out, int out_size, void* d_ws, size_t ws_size,
                              hipStream_t stream) {
  const float* x   = (const float*)d_in[0];
  const float* wq  = (const float*)d_in[2];
  const float* bq  = (const float*)d_in[3];
  const float* wk  = (const float*)d_in[4];
  const float* bk  = (const float*)d_in[5];
  const float* wv  = (const float*)d_in[6];
  const float* bv  = (const float*)d_in[7];
  const float* wo  = (const float*)d_in[8];
  const float* bo  = (const float*)d_in[9];
  const float* g1  = (const float*)d_in[10];
  const float* be1 = (const float*)d_in[11];
  const float* g2  = (const float*)d_in[12];
  const float* be2 = (const float*)d_in[13];
  const float* w1  = (const float*)d_in[14];
  const float* bb1 = (const float*)d_in[15];
  const float* w2  = (const float*)d_in[16];
  const float* bb2 = (const float*)d_in[17];

  float* outx = (float*)d_out;                       // [4096][2048] (also x1 scratch)
  float* outk = outx + (size_t)MROWS * DIMSZ;        // [4096][128]
  float* outv = outk + (size_t)MROWS * HD;           // [4096][128]

  char* p = (char*)d_ws;
  auto alloc = [&](size_t bytes) -> char* {
    char* r = p;
    p += (bytes + 255) & ~(size_t)255;
    return r;
  };
  bf16_t* wqkvT = (bf16_t*)alloc((size_t)NQKV * DIMSZ * 2);   // [2304][2048]
  bf16_t* woT = (bf16_t*)alloc((size_t)DIMSZ * DIMSZ * 2);
  bf16_t* w1T = (bf16_t*)alloc((size_t)FFDIM * DIMSZ * 2);
  bf16_t* w2T = (bf16_t*)alloc((size_t)DIMSZ * FFDIM * 2);
  bf16_t* hb  = (bf16_t*)alloc((size_t)MROWS * DIMSZ * 2);  // h, later ctx
  bf16_t* qb  = (bf16_t*)alloc((size_t)MROWS * DIMSZ * 2);  // q, later h2
  bf16_t* kbf = (bf16_t*)alloc((size_t)MROWS * HD * 2);
  bf16_t* vbf = (bf16_t*)alloc((size_t)MROWS * HD * 2);
  bf16_t* vtb = (bf16_t*)alloc((size_t)BATCH * HD * SEQ * 2);
  bf16_t* f1b = (bf16_t*)alloc((size_t)MROWS * FFDIM * 2);
  (void)ws_size; (void)in_sizes; (void)n_in; (void)out_size;

  dim3 blk(256);
  const int LDS4 = 131072;  // FN=4 (BN=256): A 64KB + B 64KB
  const int LDS2 = 98304;   // FN=2 (BN=128): A 64KB + B 32KB
  // weight transposes / bf16 conversion; wq/wk/wv land in one [2304][2048]
  k_transpose_f32_bf16<<<dim3(DIMSZ / 32, DIMSZ / 32), blk, 0, stream>>>(wq, wqkvT, DIMSZ, DIMSZ);
  k_transpose_f32_bf16<<<dim3(HD / 32, DIMSZ / 32), blk, 0, stream>>>(wk, wqkvT + (size_t)2048 * DIMSZ, DIMSZ, HD);
  k_transpose_f32_bf16<<<dim3(HD / 32, DIMSZ / 32), blk, 0, stream>>>(wv, wqkvT + (size_t)2176 * DIMSZ, DIMSZ, HD);
  k_transpose_f32_bf16<<<dim3(DIMSZ / 32, DIMSZ / 32), blk, 0, stream>>>(wo, woT, DIMSZ, DIMSZ);
  k_transpose_f32_bf16<<<dim3(FFDIM / 32, DIMSZ / 32), blk, 0, stream>>>(w1, w1T, DIMSZ, FFDIM);
  k_transpose_f32_bf16<<<dim3(DIMSZ / 32, FFDIM / 32), blk, 0, stream>>>(w2, w2T, FFDIM, DIMSZ);
  // ln1: x -> h(bf16)
  k_layernorm<<<MROWS, blk, 0, stream>>>(x, g1, be1, hb);
  // fused q,k,v projection (N=2304, 16x9 = 144 blocks)
  k_gemm8_qkv<<<(MROWS / 256) * (NQKV / 256), 512, LDS4, stream>>>(
      hb, wqkvT, bq, bk, bv, qb, outk, outv, kbf, vbf, DIMSZ);
  k_transpose_v<<<dim3(SEQ / 32, HD / 32, BATCH), blk, 0, stream>>>(vbf, vtb);
  // attention -> ctx (reuse hb)
  k_attn<<<dim3(SEQ / 64 / 2, NH, BATCH), blk, 0, stream>>>(qb, kbf, vtb, hb);
  // o-proj + residual -> outx (x1): BN=128 -> 16x16 = 256 blocks
  k_gemm8<2, 6><<<(MROWS / 256) * (DIMSZ / 128), 512, LDS2, stream>>>(
      hb, woT, bo, x, outx, nullptr, DIMSZ, DIMSZ);
  // ln2: x1 -> h2 (reuse qb)
  k_layernorm<<<MROWS, blk, 0, stream>>>(outx, g2, be2, qb);
  // ffn1 + exact gelu -> f1b (bf16): BN=256 -> 16x32 = 512 blocks
  k_gemm8<4, 9><<<(MROWS / 256) * (FFDIM / 256), 512, LDS4, stream>>>(
      qb, w1T, bb1, nullptr, nullptr, f1b, FFDIM, DIMSZ);
  // ffn2 + residual -> outx (final x): BN=128, K=8192 -> 256 blocks
  k_gemm8<2, 6><<<(MROWS / 256) * (DIMSZ / 128), 512, LDS2, stream>>>(
      f1b, w2T, bb2, outx, outx, nullptr, DIMSZ, FFDIM);
}

// Round 7
// 585.050 us; speedup vs baseline: 1.0162x; 1.0162x over previous
//
#include <hip/hip_runtime.h>
#include <stdint.h>

#define DIMSZ 2048
#define HD 128
#define NH 16
#define BATCH 2
#define SEQ 2048
#define MROWS (BATCH*SEQ)   // 4096
#define FFDIM (4*DIMSZ)     // 8192
#define NQKV (DIMSZ + 2*HD) // 2304

typedef float f32x4 __attribute__((ext_vector_type(4)));
typedef __bf16 bf16x8 __attribute__((ext_vector_type(8)));
typedef __bf16 bf16_t;

__device__ __forceinline__ void async16(const void* g, void* l) {
  __builtin_amdgcn_global_load_lds(
      (const __attribute__((address_space(1))) void*)(uintptr_t)g,
      (__attribute__((address_space(3))) void*)(uint32_t)(uintptr_t)l,
      16, 0, 0);
}

__device__ __forceinline__ float gelu_f(float x) {
  return 0.5f * x * (1.0f + erff(x * 0.70710678118654752f));
}

__device__ __forceinline__ void hard_barrier() {
  asm volatile("" ::: "memory");
  __builtin_amdgcn_s_barrier();
  asm volatile("" ::: "memory");
}

// ---------------- transpose f32 (R x C) -> bf16 (C x R) ----------------
__global__ __launch_bounds__(256)
void k_transpose_f32_bf16(const float* __restrict__ src, bf16_t* __restrict__ dst,
                          int R, int C) {
  __shared__ float tile[32][33];
  int c0 = blockIdx.x * 32, r0 = blockIdx.y * 32;
  int tx = threadIdx.x & 31, ty = threadIdx.x >> 5;
#pragma unroll
  for (int i = 0; i < 32; i += 8)
    tile[ty + i][tx] = src[(size_t)(r0 + ty + i) * C + (c0 + tx)];
  __syncthreads();
#pragma unroll
  for (int i = 0; i < 32; i += 8)
    dst[(size_t)(c0 + ty + i) * R + (r0 + tx)] = (bf16_t)tile[tx][ty + i];
}

// ---------------- transpose v bf16 [B*T][128] -> vt [B][128][T] ----------------
__global__ __launch_bounds__(256)
void k_transpose_v(const bf16_t* __restrict__ v, bf16_t* __restrict__ vt) {
  __shared__ bf16_t tile[32][33];
  int b = blockIdx.z;
  int t0 = blockIdx.x * 32, d0 = blockIdx.y * 32;
  int tx = threadIdx.x & 31, ty = threadIdx.x >> 5;
#pragma unroll
  for (int i = 0; i < 32; i += 8)
    tile[ty + i][tx] = v[((size_t)(b * SEQ + t0 + ty + i)) * HD + d0 + tx];
  __syncthreads();
#pragma unroll
  for (int i = 0; i < 32; i += 8)
    vt[((size_t)(b * HD + d0 + ty + i)) * SEQ + t0 + tx] = tile[tx][ty + i];
}

// ---------------- layernorm f32 -> bf16 ----------------
__global__ __launch_bounds__(256)
void k_layernorm(const float* __restrict__ x, const float* __restrict__ g,
                 const float* __restrict__ bb, bf16_t* __restrict__ out) {
  int row = blockIdx.x;
  const float* xr = x + (size_t)row * DIMSZ;
  int t = threadIdx.x;
  float vals[8];
  float s = 0.f, s2 = 0.f;
#pragma unroll
  for (int i = 0; i < 8; ++i) {
    float v = xr[t + i * 256];
    vals[i] = v; s += v; s2 += v * v;
  }
#pragma unroll
  for (int o = 1; o < 64; o <<= 1) { s += __shfl_xor(s, o); s2 += __shfl_xor(s2, o); }
  __shared__ float red[8];
  if ((t & 63) == 0) { red[t >> 6] = s; red[4 + (t >> 6)] = s2; }
  __syncthreads();
  s = red[0] + red[1] + red[2] + red[3];
  s2 = red[4] + red[5] + red[6] + red[7];
  float mu = s * (1.0f / DIMSZ);
  float rstd = rsqrtf(s2 * (1.0f / DIMSZ) - mu * mu + 1e-5f);
  bf16_t* orow = out + (size_t)row * DIMSZ;
#pragma unroll
  for (int i = 0; i < 8; ++i) {
    int c = t + i * 256;
    orow[c] = (bf16_t)((vals[i] - mu) * rstd * g[c] + bb[c]);
  }
}

// =====================================================================
// 8-phase 256xBN GEMM main loop (T2+T3+T4+T5 stack, plain HIP).
// FN = n-frags per wave (4 -> BN=256, 2 -> BN=128). BK=64, 512 threads,
// 8 waves (2M x 4N), per-wave output 128 x FN*16.
// ld = row stride (elements) of A and BT; Kloop = columns to process
// (callers pre-offset A/BT by the split-K column offset).
// LDS: A [2buf][2half][128][64], B [2buf][BH half][128][64], BH=FN/2.
// XOR swizzle: phys col = logical col ^ ((row&7)<<3); applied on the
// global SOURCE address of global_load_lds (dest linear) and on ds_read.
// CORRECTNESS INVARIANT: all ds_reads of a buffer happen in phases BEFORE
// any stage that overwrites it is issued (B of tile c is read ENTIRELY in
// P1/P5, before P2/P6 stage into it). Do not split ldb across phases.
//   vmcnt(6) [BH=2] / vmcnt(4) [BH=1] at P4 and P8 only; vmcnt(0) at P4
//   of the last iteration. Raw s_barrier x2 per phase; setprio around MFMA.
// =====================================================================
template <int FN>
__device__ __forceinline__ void gemm8_loop(
    const bf16_t* __restrict__ A, const bf16_t* __restrict__ BT,
    int ld, int Kloop, int bm, int bn, f32x4 (&acc)[8][FN], bf16_t* sh) {
  constexpr int BH = FN >> 1;
  constexpr int BN = FN * 64;
  const int tid = threadIdx.x;
  const int lane = tid & 63, lr = lane & 15, lg = lane >> 4;
  const int wave = tid >> 6, wm = wave >> 2, wn = wave & 3;
  bf16_t* const Ab0 = sh;            // [(c*2+h)*8192]
  bf16_t* const Bb0 = sh + 32768;    // [(c*BH+h)*8192]
  const bf16_t* const Ag = A + (size_t)bm * 256 * ld;
  const bf16_t* const Bg = BT + (size_t)bn * BN * ld;

  auto stage = [&](const bf16_t* gbase, bf16_t* lbase, int h, int t) {
#pragma unroll
    for (int j = 0; j < 2; ++j) {
      int flat = (tid + j * 512) * 8;
      int r = flat >> 6, kp = flat & 63;
      int ks = kp ^ ((r & 7) << 3);
      async16(gbase + (size_t)(h * 128 + r) * ld + t * 64 + ks, lbase + flat);
    }
  };
  auto stA = [&](int c, int h, int t) { stage(Ag, Ab0 + (c * 2 + h) * 8192, h, t); };
  auto stB = [&](int c, int h, int t) { stage(Bg, Bb0 + (c * BH + h) * 8192, h, t); };

  const int xsw = (lr & 7) << 3;
  bf16x8 a_[8], b_[FN][2];
  auto lda = [&](int c, int kk) {
    const bf16_t* base = Ab0 + (c * 2 + wm) * 8192;
#pragma unroll
    for (int mf = 0; mf < 8; ++mf)
      a_[mf] = *(const bf16x8*)(base + (mf * 16 + lr) * 64 + ((kk + lg * 8) ^ xsw));
  };
  auto ldb = [&](int c) {
#pragma unroll
    for (int nf = 0; nf < FN; ++nf) {
      int row = wn * (FN * 16) + nf * 16 + lr;
      const bf16_t* base =
          Bb0 + (c * BH + (BH == 2 ? (row >> 7) : 0)) * 8192 + (row & 127) * 64;
#pragma unroll
      for (int kx = 0; kx < 2; ++kx)
        b_[nf][kx] = *(const bf16x8*)(base + ((kx * 32 + lg * 8) ^ xsw));
    }
  };

#define LGKM0 asm volatile("s_waitcnt lgkmcnt(0)" ::: "memory");
#define VMC_STEADY                                                   \
  if (BH == 2) { asm volatile("s_waitcnt vmcnt(6)" ::: "memory"); }  \
  else         { asm volatile("s_waitcnt vmcnt(4)" ::: "memory"); }
#define MFMA_HALF(M0, KX)                                            \
  __builtin_amdgcn_s_setprio(1);                                     \
  _Pragma("unroll")                                                  \
  for (int mf = 0; mf < 4; ++mf)                                     \
    _Pragma("unroll")                                                \
    for (int nf = 0; nf < FN; ++nf)                                  \
      acc[(M0) + mf][nf] = __builtin_amdgcn_mfma_f32_16x16x32_bf16(  \
          a_[(M0) + mf], b_[nf][KX], acc[(M0) + mf][nf], 0, 0, 0);   \
  __builtin_amdgcn_s_setprio(0);

  const int nit = Kloop >> 7;  // 2 K-tiles (of 64) per iteration

  // ---- prologue: T0 all halves, then T1.{B0[,B1],A0} ----
  stA(0, 0, 0); stA(0, 1, 0);
  stB(0, 0, 0); if (BH == 2) stB(0, 1, 0);
  stB(1, 0, 1); if (BH == 2) stB(1, 1, 1);
  stA(1, 0, 1);
  VMC_STEADY;
  hard_barrier();

  for (int i = 0; i < nit; ++i) {
    const int t1 = 2 * i + 1, t2 = 2 * i + 2, t3 = 2 * i + 3;
    const bool g2 = (i < nit - 1);
    // ---- P1 ----
    lda(0, 0); ldb(0);
    stA(1, 1, t1);
    hard_barrier(); LGKM0;
    MFMA_HALF(0, 0)
    hard_barrier();
    // ---- P2 ----
    if (g2) stB(0, 0, t2);
    hard_barrier();
    MFMA_HALF(4, 0)
    hard_barrier();
    // ---- P3 ----
    lda(0, 32);
    if (g2 && BH == 2) stB(0, 1, t2);
    hard_barrier(); LGKM0;
    MFMA_HALF(0, 1)
    hard_barrier();
    // ---- P4 ----
    if (g2) stA(0, 0, t2);
    if (i == nit - 1) { asm volatile("s_waitcnt vmcnt(0)" ::: "memory"); }
    else { VMC_STEADY; }
    hard_barrier();
    MFMA_HALF(4, 1)
    hard_barrier();
    // ---- P5 ----
    lda(1, 0); ldb(1);
    if (g2) stA(0, 1, t2);
    hard_barrier(); LGKM0;
    MFMA_HALF(0, 0)
    hard_barrier();
    // ---- P6 ----
    if (g2) stB(1, 0, t3);
    hard_barrier();
    MFMA_HALF(4, 0)
    hard_barrier();
    // ---- P7 ----
    lda(1, 32);
    if (g2 && BH == 2) stB(1, 1, t3);
    hard_barrier(); LGKM0;
    MFMA_HALF(0, 1)
    hard_barrier();
    // ---- P8 ----
    if (g2) {
      stA(1, 0, t3);
      VMC_STEADY;
    }
    hard_barrier();
    MFMA_HALF(4, 1)
    hard_barrier();
  }
#undef LGKM0
#undef VMC_STEADY
#undef MFMA_HALF
}

// ---------------- o-proj: FN=2, N=2048, K=2048, out = acc + bo + x ----------
__global__ __launch_bounds__(512, 1)
void k_oproj(const bf16_t* __restrict__ A, const bf16_t* __restrict__ BT,
             const float* __restrict__ bias, const float* __restrict__ res,
             float* __restrict__ outF) {
  extern __shared__ __align__(16) bf16_t sh8[];
  const int nt = DIMSZ / 128;  // 16
  int bm = blockIdx.x / nt, bn = blockIdx.x % nt;
  f32x4 acc[8][2] = {};
  gemm8_loop<2>(A, BT, DIMSZ, DIMSZ, bm, bn, acc, sh8);
  int tid = threadIdx.x, wave = tid >> 6, lane = tid & 63, lr = lane & 15, lg = lane >> 4;
  int wm = wave >> 2, wn = wave & 3;
  int row0 = bm * 256 + wm * 128 + lg * 4;
  int col0 = bn * 128 + wn * 32 + lr;
#pragma unroll
  for (int nf = 0; nf < 2; ++nf) {
    int c = col0 + nf * 16;
    float bi = bias[c];
#pragma unroll
    for (int mf = 0; mf < 8; ++mf)
#pragma unroll
      for (int j = 0; j < 4; ++j) {
        int r = row0 + mf * 16 + j;
        size_t idx = (size_t)r * DIMSZ + c;
        outF[idx] = acc[mf][nf][j] + bi + res[idx];
      }
  }
}

// ---------------- ffn1: FN=4, N=8192, K=2048, out = gelu(acc + b1) bf16 -----
__global__ __launch_bounds__(512, 1)
void k_ffn1(const bf16_t* __restrict__ A, const bf16_t* __restrict__ BT,
            const float* __restrict__ bias, bf16_t* __restrict__ outB) {
  extern __shared__ __align__(16) bf16_t sh8[];
  const int nt = FFDIM / 256;  // 32
  int bm = blockIdx.x / nt, bn = blockIdx.x % nt;
  f32x4 acc[8][4] = {};
  gemm8_loop<4>(A, BT, DIMSZ, DIMSZ, bm, bn, acc, sh8);
  int tid = threadIdx.x, wave = tid >> 6, lane = tid & 63, lr = lane & 15, lg = lane >> 4;
  int wm = wave >> 2, wn = wave & 3;
  int row0 = bm * 256 + wm * 128 + lg * 4;
  int col0 = bn * 256 + wn * 64 + lr;
#pragma unroll
  for (int nf = 0; nf < 4; ++nf) {
    int c = col0 + nf * 16;
    float bi = bias[c];
#pragma unroll
    for (int mf = 0; mf < 8; ++mf)
#pragma unroll
      for (int j = 0; j < 4; ++j) {
        int r = row0 + mf * 16 + j;
        outB[(size_t)r * FFDIM + c] = (bf16_t)gelu_f(acc[mf][nf][j] + bi);
      }
  }
}

// ---------------- ffn2: FN=4 split-K x2, N=2048, K=8192 ----------------
// outx already holds x1; each half atomically adds its partial (+b2 on kh=0).
__global__ __launch_bounds__(512, 1)
void k_ffn2(const bf16_t* __restrict__ A, const bf16_t* __restrict__ BT,
            const float* __restrict__ bias, float* __restrict__ outF) {
  extern __shared__ __align__(16) bf16_t sh8[];
  int bid = blockIdx.x;
  int kh = bid >> 7;            // 128 tiles of 256x256 per K-half
  int tile = bid & 127;
  int bm = tile >> 3, bn = tile & 7;   // 16 x 8
  f32x4 acc[8][4] = {};
  gemm8_loop<4>(A + kh * (FFDIM / 2), BT + kh * (FFDIM / 2), FFDIM, FFDIM / 2,
                bm, bn, acc, sh8);
  int tid = threadIdx.x, wave = tid >> 6, lane = tid & 63, lr = lane & 15, lg = lane >> 4;
  int wm = wave >> 2, wn = wave & 3;
  int row0 = bm * 256 + wm * 128 + lg * 4;
  int col0 = bn * 256 + wn * 64 + lr;
#pragma unroll
  for (int nf = 0; nf < 4; ++nf) {
    int c = col0 + nf * 16;
    float bi = kh ? 0.f : bias[c];
#pragma unroll
    for (int mf = 0; mf < 8; ++mf)
#pragma unroll
      for (int j = 0; j < 4; ++j) {
        int r = row0 + mf * 16 + j;
        __hip_atomic_fetch_add(&outF[(size_t)r * DIMSZ + c], acc[mf][nf][j] + bi,
                               __ATOMIC_RELAXED, __HIP_MEMORY_SCOPE_AGENT);
      }
  }
}

// ---------------- fused QKV 8-phase GEMM: N = 2304 (2048 q|128 k|128 v) ------
__global__ __launch_bounds__(512, 1)
void k_qkv(const bf16_t* __restrict__ A, const bf16_t* __restrict__ BT,
           const float* __restrict__ bq, const float* __restrict__ bk,
           const float* __restrict__ bv,
           bf16_t* __restrict__ qb, float* __restrict__ outk,
           float* __restrict__ outv, bf16_t* __restrict__ kbf,
           bf16_t* __restrict__ vbf) {
  extern __shared__ __align__(16) bf16_t sh8[];
  const int nt = NQKV / 256;  // 9
  int bm = blockIdx.x / nt, bn = blockIdx.x % nt;
  f32x4 acc[8][4] = {};
  gemm8_loop<4>(A, BT, DIMSZ, DIMSZ, bm, bn, acc, sh8);
  int tid = threadIdx.x, wave = tid >> 6, lane = tid & 63, lr = lane & 15, lg = lane >> 4;
  int wm = wave >> 2, wn = wave & 3;
  int row0 = bm * 256 + wm * 128 + lg * 4;
  int col0 = bn * 256 + wn * 64 + lr;
#pragma unroll
  for (int nf = 0; nf < 4; ++nf) {
    int c = col0 + nf * 16;
    float bi = (c < 2048) ? bq[c] : (c < 2176 ? bk[c - 2048] : bv[c - 2176]);
#pragma unroll
    for (int mf = 0; mf < 8; ++mf) {
#pragma unroll
      for (int j = 0; j < 4; ++j) {
        int r = row0 + mf * 16 + j;
        float v = acc[mf][nf][j] + bi;
        if (c < 2048) {
          qb[(size_t)r * DIMSZ + c] = (bf16_t)v;
        } else if (c < 2176) {
          int cc = c - 2048;
          outk[(size_t)r * HD + cc] = v;
          kbf[(size_t)r * HD + cc] = (bf16_t)v;
        } else {
          int cc = c - 2176;
          outv[(size_t)r * HD + cc] = v;
          vbf[(size_t)r * HD + cc] = (bf16_t)v;
        }
      }
    }
  }
}

// ---------------- causal flash attention (MQA) ----------------
__global__ __launch_bounds__(256, 2)
void k_attn(const bf16_t* __restrict__ q, const bf16_t* __restrict__ k,
            const bf16_t* __restrict__ vt, bf16_t* __restrict__ ctx) {
  __shared__ __align__(16) bf16_t Ks[2][64 * 128];
  __shared__ __align__(16) bf16_t Vs[2][128 * 64];
  __shared__ bf16_t Pw[4][16][72];
  int pp = blockIdx.x, h = blockIdx.y, b = blockIdx.z;
  int tid = threadIdx.x, wave = tid >> 6, lane = tid & 63, lr = lane & 15, lg = lane >> 4;
  const bf16_t* kb = k + (size_t)b * SEQ * HD;
  const bf16_t* vb = vt + (size_t)b * HD * SEQ;

#define STAGE_TILE(buf, s0_)                                                      \
  {                                                                               \
    _Pragma("unroll")                                                             \
    for (int i = 0; i < 4; ++i) {                                                 \
      int flat = (i * 256 + tid) * 8;                                             \
      int kr = flat >> 7, kc = flat & 127;                                        \
      int ksrc = (((kc >> 3) ^ (kr & 7)) << 3) | (kc & 7);                        \
      async16(kb + (size_t)((s0_) + kr) * HD + ksrc, (void*)(Ks[buf] + flat));    \
      int vr = flat >> 6, vc = flat & 63;                                         \
      int vsrc = (((vc >> 3) ^ (vr & 7)) << 3) | (vc & 7);                        \
      async16(vb + (size_t)vr * SEQ + (s0_) + vsrc, (void*)(Vs[buf] + flat));     \
    }                                                                             \
  }

  for (int half = 0; half < 2; ++half) {
    int qt = half ? (31 - pp) : pp;
    int q0 = qt * 64;
    int qw = q0 + wave * 16;
    const bf16_t* qbase = q + ((size_t)(b * SEQ + qw + lr)) * DIMSZ + h * HD;
    bf16x8 qf[4];
#pragma unroll
    for (int kk = 0; kk < 4; ++kk) qf[kk] = *(const bf16x8*)(qbase + kk * 32 + lg * 8);
    f32x4 o[8] = {};
    float m_[4], l_[4];
#pragma unroll
    for (int j = 0; j < 4; ++j) { m_[j] = -3.0e38f; l_[j] = 0.f; }
    int qglob0 = qw + lg * 4;
    int ntiles = qt + 1;

    STAGE_TILE(0, 0)
    __syncthreads();
    for (int t = 0; t < ntiles; ++t) {
      int cur = t & 1;
      if (t + 1 < ntiles) STAGE_TILE(cur ^ 1, (t + 1) * 64)
      int s0 = t * 64;
      const bf16_t* Kc = Ks[cur];
      const bf16_t* Vc = Vs[cur];
      f32x4 sf[4] = {};
#pragma unroll
      for (int nf = 0; nf < 4; ++nf) {
        int R = nf * 16 + lr;
#pragma unroll
        for (int kk = 0; kk < 4; ++kk)
          sf[nf] = __builtin_amdgcn_mfma_f32_16x16x32_bf16(
              qf[kk],
              *(const bf16x8*)(Kc + R * 128 + (((kk * 4 + lg) ^ (R & 7)) << 3)),
              sf[nf], 0, 0, 0);
      }
#pragma unroll
      for (int nf = 0; nf < 4; ++nf) {
        int col = s0 + nf * 16 + lr;
#pragma unroll
        for (int j = 0; j < 4; ++j) {
          float v = sf[nf][j] * 0.088388347648318447f;
          sf[nf][j] = (col <= qglob0 + j) ? v : -3.0e38f;
        }
      }
      float mx[4];
#pragma unroll
      for (int j = 0; j < 4; ++j)
        mx[j] = fmaxf(fmaxf(sf[0][j], sf[1][j]), fmaxf(sf[2][j], sf[3][j]));
#pragma unroll
      for (int o_ = 1; o_ < 16; o_ <<= 1)
#pragma unroll
        for (int j = 0; j < 4; ++j) mx[j] = fmaxf(mx[j], __shfl_xor(mx[j], o_));
      float fsc[4], mn[4];
#pragma unroll
      for (int j = 0; j < 4; ++j) {
        mn[j] = fmaxf(m_[j], mx[j]);
        fsc[j] = __expf(m_[j] - mn[j]);
        m_[j] = mn[j];
      }
      float ps[4] = {0.f, 0.f, 0.f, 0.f};
#pragma unroll
      for (int nf = 0; nf < 4; ++nf)
#pragma unroll
        for (int j = 0; j < 4; ++j) {
          float pv = __expf(sf[nf][j] - mn[j]);
          ps[j] += pv;
          Pw[wave][lg * 4 + j][nf * 16 + lr] = (bf16_t)pv;
        }
#pragma unroll
      for (int o_ = 1; o_ < 16; o_ <<= 1)
#pragma unroll
        for (int j = 0; j < 4; ++j) ps[j] += __shfl_xor(ps[j], o_);
#pragma unroll
      for (int j = 0; j < 4; ++j) l_[j] = l_[j] * fsc[j] + ps[j];
#pragma unroll
      for (int df = 0; df < 8; ++df)
#pragma unroll
        for (int j = 0; j < 4; ++j) o[df][j] *= fsc[j];
      asm volatile("" ::: "memory");
      bf16x8 pa[2];
#pragma unroll
      for (int kk = 0; kk < 2; ++kk)
        pa[kk] = *(const bf16x8*)(&Pw[wave][lr][kk * 32 + lg * 8]);
#pragma unroll
      for (int df = 0; df < 8; ++df) {
        int R = df * 16 + lr;
#pragma unroll
        for (int kk = 0; kk < 2; ++kk)
          o[df] = __builtin_amdgcn_mfma_f32_16x16x32_bf16(
              pa[kk],
              *(const bf16x8*)(Vc + R * 64 + (((kk * 4 + lg) ^ (R & 7)) << 3)),
              o[df], 0, 0, 0);
      }
      __syncthreads();
    }
    bf16_t* cb = ctx + ((size_t)(b * SEQ + qw)) * DIMSZ + h * HD;
#pragma unroll
    for (int df = 0; df < 8; ++df)
#pragma unroll
      for (int j = 0; j < 4; ++j)
        cb[(size_t)(lg * 4 + j) * DIMSZ + df * 16 + lr] = (bf16_t)(o[df][j] / l_[j]);
  }
#undef STAGE_TILE
}

extern "C" void kernel_launch(void* const* d_in, const int* in_sizes, int n_in,
                              void* d_out, int out_size, void* d_ws, size_t ws_size,
                              hipStream_t stream) {
  const float* x   = (const float*)d_in[0];
  const float* wq  = (const float*)d_in[2];
  const float* bq  = (const float*)d_in[3];
  const float* wk  = (const float*)d_in[4];
  const float* bk  = (const float*)d_in[5];
  const float* wv  = (const float*)d_in[6];
  const float* bv  = (const float*)d_in[7];
  const float* wo  = (const float*)d_in[8];
  const float* bo  = (const float*)d_in[9];
  const float* g1  = (const float*)d_in[10];
  const float* be1 = (const float*)d_in[11];
  const float* g2  = (const float*)d_in[12];
  const float* be2 = (const float*)d_in[13];
  const float* w1  = (const float*)d_in[14];
  const float* bb1 = (const float*)d_in[15];
  const float* w2  = (const float*)d_in[16];
  const float* bb2 = (const float*)d_in[17];

  float* outx = (float*)d_out;                       // [4096][2048] (also x1 scratch)
  float* outk = outx + (size_t)MROWS * DIMSZ;        // [4096][128]
  float* outv = outk + (size_t)MROWS * HD;           // [4096][128]

  char* p = (char*)d_ws;
  auto alloc = [&](size_t bytes) -> char* {
    char* r = p;
    p += (bytes + 255) & ~(size_t)255;
    return r;
  };
  bf16_t* wqkvT = (bf16_t*)alloc((size_t)NQKV * DIMSZ * 2);   // [2304][2048]
  bf16_t* woT = (bf16_t*)alloc((size_t)DIMSZ * DIMSZ * 2);
  bf16_t* w1T = (bf16_t*)alloc((size_t)FFDIM * DIMSZ * 2);
  bf16_t* w2T = (bf16_t*)alloc((size_t)DIMSZ * FFDIM * 2);
  bf16_t* hb  = (bf16_t*)alloc((size_t)MROWS * DIMSZ * 2);  // h, later ctx
  bf16_t* qb  = (bf16_t*)alloc((size_t)MROWS * DIMSZ * 2);  // q, later h2
  bf16_t* kbf = (bf16_t*)alloc((size_t)MROWS * HD * 2);
  bf16_t* vbf = (bf16_t*)alloc((size_t)MROWS * HD * 2);
  bf16_t* vtb = (bf16_t*)alloc((size_t)BATCH * HD * SEQ * 2);
  bf16_t* f1b = (bf16_t*)alloc((size_t)MROWS * FFDIM * 2);
  (void)ws_size; (void)in_sizes; (void)n_in; (void)out_size;

  dim3 blk(256);
  const int LDS4 = 131072;  // FN=4 (BN=256): A 64KB + B 64KB
  const int LDS2 = 98304;   // FN=2 (BN=128): A 64KB + B 32KB
  // weight transposes / bf16 conversion; wq/wk/wv land in one [2304][2048]
  k_transpose_f32_bf16<<<dim3(DIMSZ / 32, DIMSZ / 32), blk, 0, stream>>>(wq, wqkvT, DIMSZ, DIMSZ);
  k_transpose_f32_bf16<<<dim3(HD / 32, DIMSZ / 32), blk, 0, stream>>>(wk, wqkvT + (size_t)2048 * DIMSZ, DIMSZ, HD);
  k_transpose_f32_bf16<<<dim3(HD / 32, DIMSZ / 32), blk, 0, stream>>>(wv, wqkvT + (size_t)2176 * DIMSZ, DIMSZ, HD);
  k_transpose_f32_bf16<<<dim3(DIMSZ / 32, DIMSZ / 32), blk, 0, stream>>>(wo, woT, DIMSZ, DIMSZ);
  k_transpose_f32_bf16<<<dim3(FFDIM / 32, DIMSZ / 32), blk, 0, stream>>>(w1, w1T, DIMSZ, FFDIM);
  k_transpose_f32_bf16<<<dim3(DIMSZ / 32, FFDIM / 32), blk, 0, stream>>>(w2, w2T, FFDIM, DIMSZ);
  // ln1: x -> h(bf16)
  k_layernorm<<<MROWS, blk, 0, stream>>>(x, g1, be1, hb);
  // fused q,k,v projection (N=2304, 16x9 = 144 blocks)
  k_qkv<<<(MROWS / 256) * (NQKV / 256), 512, LDS4, stream>>>(
      hb, wqkvT, bq, bk, bv, qb, outk, outv, kbf, vbf);
  k_transpose_v<<<dim3(SEQ / 32, HD / 32, BATCH), blk, 0, stream>>>(vbf, vtb);
  // attention -> ctx (reuse hb)
  k_attn<<<dim3(SEQ / 64 / 2, NH, BATCH), blk, 0, stream>>>(qb, kbf, vtb, hb);
  // o-proj + residual -> outx (x1): FN=2, 16x16 = 256 blocks
  k_oproj<<<(MROWS / 256) * (DIMSZ / 128), 512, LDS2, stream>>>(hb, woT, bo, x, outx);
  // ln2: x1 -> h2 (reuse qb)
  k_layernorm<<<MROWS, blk, 0, stream>>>(outx, g2, be2, qb);
  // ffn1 + exact gelu -> f1b (bf16): FN=4, 16x32 = 512 blocks
  k_ffn1<<<(MROWS / 256) * (FFDIM / 256), 512, LDS4, stream>>>(qb, w1T, bb1, f1b);
  // ffn2 split-K x2: 256 blocks, atomic accumulate onto outx (holds x1)
  k_ffn2<<<256, 512, LDS4, stream>>>(f1b, w2T, bb2, outx);
}

// Round 8
// 560.868 us; speedup vs baseline: 1.0600x; 1.0431x over previous
//
#include <hip/hip_runtime.h>
#include <stdint.h>

#define DIMSZ 2048
#define HD 128
#define NH 16
#define BATCH 2
#define SEQ 2048
#define MROWS (BATCH*SEQ)   // 4096
#define FFDIM (4*DIMSZ)     // 8192
#define NQKV (DIMSZ + 2*HD) // 2304

typedef float f32x4 __attribute__((ext_vector_type(4)));
typedef __bf16 bf16x8 __attribute__((ext_vector_type(8)));
typedef __bf16 bf16x2 __attribute__((ext_vector_type(2)));
typedef __bf16 bf16_t;

__device__ __forceinline__ void async16(const void* g, void* l) {
  __builtin_amdgcn_global_load_lds(
      (const __attribute__((address_space(1))) void*)(uintptr_t)g,
      (__attribute__((address_space(3))) void*)(uint32_t)(uintptr_t)l,
      16, 0, 0);
}

__device__ __forceinline__ float gelu_f(float x) {
  return 0.5f * x * (1.0f + erff(x * 0.70710678118654752f));
}

__device__ __forceinline__ void hard_barrier() {
  asm volatile("" ::: "memory");
  __builtin_amdgcn_s_barrier();
  asm volatile("" ::: "memory");
}

// XCD-aware block swizzle (nwg must be divisible by 8)
__device__ __forceinline__ int xcd_swz(int bid, int nwg) {
  return (bid & 7) * (nwg >> 3) + (bid >> 3);
}

// ---------------- transpose f32 (R x C) -> bf16 (C x R), 64x64 tiles --------
__global__ __launch_bounds__(256)
void k_tr64(const float* __restrict__ src, bf16_t* __restrict__ dst,
            int R, int C) {
  __shared__ float tile[64][65];
  int c0 = blockIdx.x * 64, r0 = blockIdx.y * 64;
  int lc = threadIdx.x & 63, lrow = threadIdx.x >> 6;
#pragma unroll
  for (int i = 0; i < 64; i += 4)
    tile[lrow + i][lc] = src[(size_t)(r0 + lrow + i) * C + c0 + lc];
  __syncthreads();
  int rp = threadIdx.x & 31, wc = threadIdx.x >> 5;
#pragma unroll
  for (int i = 0; i < 64; i += 8) {
    int c = wc + i;
    bf16x2 pk = {(bf16_t)tile[2 * rp][c], (bf16_t)tile[2 * rp + 1][c]};
    *(bf16x2*)(dst + (size_t)(c0 + c) * R + r0 + 2 * rp) = pk;
  }
}

// ---------------- transpose v bf16 [B*T][128] -> vt [B][128][T] ----------------
__global__ __launch_bounds__(256)
void k_transpose_v(const bf16_t* __restrict__ v, bf16_t* __restrict__ vt) {
  __shared__ bf16_t tile[32][33];
  int b = blockIdx.z;
  int t0 = blockIdx.x * 32, d0 = blockIdx.y * 32;
  int tx = threadIdx.x & 31, ty = threadIdx.x >> 5;
#pragma unroll
  for (int i = 0; i < 32; i += 8)
    tile[ty + i][tx] = v[((size_t)(b * SEQ + t0 + ty + i)) * HD + d0 + tx];
  __syncthreads();
#pragma unroll
  for (int i = 0; i < 32; i += 8)
    vt[((size_t)(b * HD + d0 + ty + i)) * SEQ + t0 + tx] = tile[tx][ty + i];
}

// ---------------- layernorm f32 -> bf16 ----------------
__global__ __launch_bounds__(256)
void k_layernorm(const float* __restrict__ x, const float* __restrict__ g,
                 const float* __restrict__ bb, bf16_t* __restrict__ out) {
  int row = blockIdx.x;
  const float* xr = x + (size_t)row * DIMSZ;
  int t = threadIdx.x;
  float vals[8];
  float s = 0.f, s2 = 0.f;
#pragma unroll
  for (int i = 0; i < 8; ++i) {
    float v = xr[t + i * 256];
    vals[i] = v; s += v; s2 += v * v;
  }
#pragma unroll
  for (int o = 1; o < 64; o <<= 1) { s += __shfl_xor(s, o); s2 += __shfl_xor(s2, o); }
  __shared__ float red[8];
  if ((t & 63) == 0) { red[t >> 6] = s; red[4 + (t >> 6)] = s2; }
  __syncthreads();
  s = red[0] + red[1] + red[2] + red[3];
  s2 = red[4] + red[5] + red[6] + red[7];
  float mu = s * (1.0f / DIMSZ);
  float rstd = rsqrtf(s2 * (1.0f / DIMSZ) - mu * mu + 1e-5f);
  bf16_t* orow = out + (size_t)row * DIMSZ;
#pragma unroll
  for (int i = 0; i < 8; ++i) {
    int c = t + i * 256;
    orow[c] = (bf16_t)((vals[i] - mu) * rstd * g[c] + bb[c]);
  }
}

// =====================================================================
// 8-phase 256xBN GEMM main loop (unchanged from r7 — verified schedule).
// =====================================================================
template <int FN>
__device__ __forceinline__ void gemm8_loop(
    const bf16_t* __restrict__ A, const bf16_t* __restrict__ BT,
    int ld, int Kloop, int bm, int bn, f32x4 (&acc)[8][FN], bf16_t* sh) {
  constexpr int BH = FN >> 1;
  constexpr int BN = FN * 64;
  const int tid = threadIdx.x;
  const int lane = tid & 63, lr = lane & 15, lg = lane >> 4;
  const int wave = tid >> 6, wm = wave >> 2, wn = wave & 3;
  bf16_t* const Ab0 = sh;            // [(c*2+h)*8192]
  bf16_t* const Bb0 = sh + 32768;    // [(c*BH+h)*8192]
  const bf16_t* const Ag = A + (size_t)bm * 256 * ld;
  const bf16_t* const Bg = BT + (size_t)bn * BN * ld;

  auto stage = [&](const bf16_t* gbase, bf16_t* lbase, int h, int t) {
#pragma unroll
    for (int j = 0; j < 2; ++j) {
      int flat = (tid + j * 512) * 8;
      int r = flat >> 6, kp = flat & 63;
      int ks = kp ^ ((r & 7) << 3);
      async16(gbase + (size_t)(h * 128 + r) * ld + t * 64 + ks, lbase + flat);
    }
  };
  auto stA = [&](int c, int h, int t) { stage(Ag, Ab0 + (c * 2 + h) * 8192, h, t); };
  auto stB = [&](int c, int h, int t) { stage(Bg, Bb0 + (c * BH + h) * 8192, h, t); };

  const int xsw = (lr & 7) << 3;
  bf16x8 a_[8], b_[FN][2];
  auto lda = [&](int c, int kk) {
    const bf16_t* base = Ab0 + (c * 2 + wm) * 8192;
#pragma unroll
    for (int mf = 0; mf < 8; ++mf)
      a_[mf] = *(const bf16x8*)(base + (mf * 16 + lr) * 64 + ((kk + lg * 8) ^ xsw));
  };
  auto ldb = [&](int c) {
#pragma unroll
    for (int nf = 0; nf < FN; ++nf) {
      int row = wn * (FN * 16) + nf * 16 + lr;
      const bf16_t* base =
          Bb0 + (c * BH + (BH == 2 ? (row >> 7) : 0)) * 8192 + (row & 127) * 64;
#pragma unroll
      for (int kx = 0; kx < 2; ++kx)
        b_[nf][kx] = *(const bf16x8*)(base + ((kx * 32 + lg * 8) ^ xsw));
    }
  };

#define LGKM0 asm volatile("s_waitcnt lgkmcnt(0)" ::: "memory");
#define VMC_STEADY                                                   \
  if (BH == 2) { asm volatile("s_waitcnt vmcnt(6)" ::: "memory"); }  \
  else         { asm volatile("s_waitcnt vmcnt(4)" ::: "memory"); }
#define MFMA_HALF(M0, KX)                                            \
  __builtin_amdgcn_s_setprio(1);                                     \
  _Pragma("unroll")                                                  \
  for (int mf = 0; mf < 4; ++mf)                                     \
    _Pragma("unroll")                                                \
    for (int nf = 0; nf < FN; ++nf)                                  \
      acc[(M0) + mf][nf] = __builtin_amdgcn_mfma_f32_16x16x32_bf16(  \
          a_[(M0) + mf], b_[nf][KX], acc[(M0) + mf][nf], 0, 0, 0);   \
  __builtin_amdgcn_s_setprio(0);

  const int nit = Kloop >> 7;

  stA(0, 0, 0); stA(0, 1, 0);
  stB(0, 0, 0); if (BH == 2) stB(0, 1, 0);
  stB(1, 0, 1); if (BH == 2) stB(1, 1, 1);
  stA(1, 0, 1);
  VMC_STEADY;
  hard_barrier();

  for (int i = 0; i < nit; ++i) {
    const int t1 = 2 * i + 1, t2 = 2 * i + 2, t3 = 2 * i + 3;
    const bool g2 = (i < nit - 1);
    // ---- P1 ----
    lda(0, 0); ldb(0);
    stA(1, 1, t1);
    hard_barrier(); LGKM0;
    MFMA_HALF(0, 0)
    hard_barrier();
    // ---- P2 ----
    if (g2) stB(0, 0, t2);
    hard_barrier();
    MFMA_HALF(4, 0)
    hard_barrier();
    // ---- P3 ----
    lda(0, 32);
    if (g2 && BH == 2) stB(0, 1, t2);
    hard_barrier(); LGKM0;
    MFMA_HALF(0, 1)
    hard_barrier();
    // ---- P4 ----
    if (g2) stA(0, 0, t2);
    if (i == nit - 1) { asm volatile("s_waitcnt vmcnt(0)" ::: "memory"); }
    else { VMC_STEADY; }
    hard_barrier();
    MFMA_HALF(4, 1)
    hard_barrier();
    // ---- P5 ----
    lda(1, 0); ldb(1);
    if (g2) stA(0, 1, t2);
    hard_barrier(); LGKM0;
    MFMA_HALF(0, 0)
    hard_barrier();
    // ---- P6 ----
    if (g2) stB(1, 0, t3);
    hard_barrier();
    MFMA_HALF(4, 0)
    hard_barrier();
    // ---- P7 ----
    lda(1, 32);
    if (g2 && BH == 2) stB(1, 1, t3);
    hard_barrier(); LGKM0;
    MFMA_HALF(0, 1)
    hard_barrier();
    // ---- P8 ----
    if (g2) {
      stA(1, 0, t3);
      VMC_STEADY;
    }
    hard_barrier();
    MFMA_HALF(4, 1)
    hard_barrier();
  }
#undef LGKM0
#undef VMC_STEADY
#undef MFMA_HALF
}

// ---------------- o-proj: FN=2, out = acc + bo + x (f32), restaged ----------
__global__ __launch_bounds__(512, 1)
void k_oproj(const bf16_t* __restrict__ A, const bf16_t* __restrict__ BT,
             const float* __restrict__ bias, const float* __restrict__ res,
             float* __restrict__ outF) {
  extern __shared__ __align__(16) bf16_t sh8[];
  const int nt = DIMSZ / 128;  // 16
  const int nwg = (MROWS / 256) * nt;  // 256
  int swz = xcd_swz(blockIdx.x, nwg);
  int bm = swz / nt, bn = swz % nt;
  f32x4 acc[8][2] = {};
  gemm8_loop<2>(A, BT, DIMSZ, DIMSZ, bm, bn, acc, sh8);
  int tid = threadIdx.x, wave = tid >> 6, lane = tid & 63, lr = lane & 15, lg = lane >> 4;
  int wm = wave >> 2, wn = wave & 3;
  // phase A: acc+bias -> LDS f32 [256][128]
  float* shF = (float*)sh8;
  int rl0 = wm * 128 + lg * 4;
  int cl0 = wn * 32 + lr;
#pragma unroll
  for (int nf = 0; nf < 2; ++nf) {
    int cl = cl0 + nf * 16;
    float bi = bias[bn * 128 + cl];
#pragma unroll
    for (int mf = 0; mf < 8; ++mf)
#pragma unroll
      for (int j = 0; j < 4; ++j)
        shF[(rl0 + mf * 16 + j) * 128 + cl] = acc[mf][nf][j] + bi;
  }
  hard_barrier();
  // phase B: coalesced +res -> outF
  const float* rbase = res + (size_t)(bm * 256) * DIMSZ + bn * 128;
  float* gbase = outF + (size_t)(bm * 256) * DIMSZ + bn * 128;
#pragma unroll
  for (int s = 0; s < 16; ++s) {
    int flat = s * 512 + tid;           // 16B units
    int row = flat >> 5, cu = flat & 31;  // 32 units per 128-f32 row
    f32x4 v = *(const f32x4*)(shF + row * 128 + cu * 4);
    f32x4 r4 = *(const f32x4*)(rbase + (size_t)row * DIMSZ + cu * 4);
    *(f32x4*)(gbase + (size_t)row * DIMSZ + cu * 4) = v + r4;
  }
}

// ---------------- ffn1: FN=4, out = gelu(acc + b1) bf16, restaged -----------
__global__ __launch_bounds__(512, 1)
void k_ffn1(const bf16_t* __restrict__ A, const bf16_t* __restrict__ BT,
            const float* __restrict__ bias, bf16_t* __restrict__ outB) {
  extern __shared__ __align__(16) bf16_t sh8[];
  const int nt = FFDIM / 256;  // 32
  const int nwg = (MROWS / 256) * nt;  // 512
  int swz = xcd_swz(blockIdx.x, nwg);
  int bm = swz / nt, bn = swz % nt;
  f32x4 acc[8][4] = {};
  gemm8_loop<4>(A, BT, DIMSZ, DIMSZ, bm, bn, acc, sh8);
  int tid = threadIdx.x, wave = tid >> 6, lane = tid & 63, lr = lane & 15, lg = lane >> 4;
  int wm = wave >> 2, wn = wave & 3;
  // phase A: gelu(acc+bias) -> LDS bf16 [256][256]
  int rl0 = wm * 128 + lg * 4;
  int cl0 = wn * 64 + lr;
#pragma unroll
  for (int nf = 0; nf < 4; ++nf) {
    int cl = cl0 + nf * 16;
    float bi = bias[bn * 256 + cl];
#pragma unroll
    for (int mf = 0; mf < 8; ++mf)
#pragma unroll
      for (int j = 0; j < 4; ++j)
        sh8[(rl0 + mf * 16 + j) * 256 + cl] = (bf16_t)gelu_f(acc[mf][nf][j] + bi);
  }
  hard_barrier();
  // phase B: coalesced copy LDS -> outB
  bf16_t* gbase = outB + (size_t)(bm * 256) * FFDIM + bn * 256;
#pragma unroll
  for (int s = 0; s < 16; ++s) {
    int flat = s * 512 + tid;             // 16B units
    int row = flat >> 5, cu = flat & 31;  // 32 units per 256-bf16 row
    f32x4 v = *(const f32x4*)(sh8 + row * 256 + cu * 8);
    *(f32x4*)(gbase + (size_t)row * FFDIM + cu * 8) = v;
  }
}

// ---------------- ffn2: FN=4 split-K x2, atomic accumulate ----------------
__global__ __launch_bounds__(512, 1)
void k_ffn2(const bf16_t* __restrict__ A, const bf16_t* __restrict__ BT,
            const float* __restrict__ bias, float* __restrict__ outF) {
  extern __shared__ __align__(16) bf16_t sh8[];
  int swz = xcd_swz(blockIdx.x, 256);
  int kh = swz >> 7;
  int tile = swz & 127;
  int bm = tile >> 3, bn = tile & 7;   // 16 x 8
  f32x4 acc[8][4] = {};
  gemm8_loop<4>(A + kh * (FFDIM / 2), BT + kh * (FFDIM / 2), FFDIM, FFDIM / 2,
                bm, bn, acc, sh8);
  int tid = threadIdx.x, wave = tid >> 6, lane = tid & 63, lr = lane & 15, lg = lane >> 4;
  int wm = wave >> 2, wn = wave & 3;
  int row0 = bm * 256 + wm * 128 + lg * 4;
  int col0 = bn * 256 + wn * 64 + lr;
#pragma unroll
  for (int nf = 0; nf < 4; ++nf) {
    int c = col0 + nf * 16;
    float bi = kh ? 0.f : bias[c];
#pragma unroll
    for (int mf = 0; mf < 8; ++mf)
#pragma unroll
      for (int j = 0; j < 4; ++j) {
        int r = row0 + mf * 16 + j;
        __hip_atomic_fetch_add(&outF[(size_t)r * DIMSZ + c], acc[mf][nf][j] + bi,
                               __ATOMIC_RELAXED, __HIP_MEMORY_SCOPE_AGENT);
      }
  }
}

// ---------------- fused QKV: N = 2304 (2048 q | 128 k | 128 v), restaged ----
__global__ __launch_bounds__(512, 1)
void k_qkv(const bf16_t* __restrict__ A, const bf16_t* __restrict__ BT,
           const float* __restrict__ bq, const float* __restrict__ bk,
           const float* __restrict__ bv,
           bf16_t* __restrict__ qb, float* __restrict__ outk,
           float* __restrict__ outv, bf16_t* __restrict__ kbf,
           bf16_t* __restrict__ vbf) {
  extern __shared__ __align__(16) bf16_t sh8[];
  const int nt = NQKV / 256;  // 9
  const int nwg = (MROWS / 256) * nt;  // 144
  int swz = xcd_swz(blockIdx.x, nwg);
  int bm = swz / nt, bn = swz % nt;
  f32x4 acc[8][4] = {};
  gemm8_loop<4>(A, BT, DIMSZ, DIMSZ, bm, bn, acc, sh8);
  int tid = threadIdx.x, wave = tid >> 6, lane = tid & 63, lr = lane & 15, lg = lane >> 4;
  int wm = wave >> 2, wn = wave & 3;
  // phase A: acc+bias -> LDS bf16 [256][256]; f32 k/v copies stored directly
  int rl0 = wm * 128 + lg * 4;
  int cl0 = wn * 64 + lr;
#pragma unroll
  for (int nf = 0; nf < 4; ++nf) {
    int cl = cl0 + nf * 16;
    int cg = bn * 256 + cl;
    float bi = (cg < 2048) ? bq[cg] : (cg < 2176 ? bk[cg - 2048] : bv[cg - 2176]);
#pragma unroll
    for (int mf = 0; mf < 8; ++mf)
#pragma unroll
      for (int j = 0; j < 4; ++j) {
        float v = acc[mf][nf][j] + bi;
        sh8[(rl0 + mf * 16 + j) * 256 + cl] = (bf16_t)v;
        if (cg >= 2048) {
          int r = bm * 256 + rl0 + mf * 16 + j;
          if (cg < 2176) outk[(size_t)r * HD + (cg - 2048)] = v;
          else           outv[(size_t)r * HD + (cg - 2176)] = v;
        }
      }
  }
  hard_barrier();
  // phase B: coalesced LDS -> qb or kbf/vbf
#pragma unroll
  for (int s = 0; s < 16; ++s) {
    int flat = s * 512 + tid;
    int row = flat >> 5, cu = flat & 31;
    f32x4 v = *(const f32x4*)(sh8 + row * 256 + cu * 8);
    int r = bm * 256 + row;
    if (bn < 8) {
      *(f32x4*)(qb + (size_t)r * DIMSZ + bn * 256 + cu * 8) = v;
    } else {
      int ce = cu * 8;  // 0..255
      if (ce < 128) *(f32x4*)(kbf + (size_t)r * HD + ce) = v;
      else          *(f32x4*)(vbf + (size_t)r * HD + (ce - 128)) = v;
    }
  }
}

// ---------------- causal flash attention (MQA) ----------------
__global__ __launch_bounds__(256, 2)
void k_attn(const bf16_t* __restrict__ q, const bf16_t* __restrict__ k,
            const bf16_t* __restrict__ vt, bf16_t* __restrict__ ctx) {
  __shared__ __align__(16) bf16_t Ks[2][64 * 128];
  __shared__ __align__(16) bf16_t Vs[2][128 * 64];
  __shared__ bf16_t Pw[4][16][72];
  int pp = blockIdx.x, h = blockIdx.y, b = blockIdx.z;
  int tid = threadIdx.x, wave = tid >> 6, lane = tid & 63, lr = lane & 15, lg = lane >> 4;
  const bf16_t* kb = k + (size_t)b * SEQ * HD;
  const bf16_t* vb = vt + (size_t)b * HD * SEQ;

#define STAGE_TILE(buf, s0_)                                                      \
  {                                                                               \
    _Pragma("unroll")                                                             \
    for (int i = 0; i < 4; ++i) {                                                 \
      int flat = (i * 256 + tid) * 8;                                             \
      int kr = flat >> 7, kc = flat & 127;                                        \
      int ksrc = (((kc >> 3) ^ (kr & 7)) << 3) | (kc & 7);                        \
      async16(kb + (size_t)((s0_) + kr) * HD + ksrc, (void*)(Ks[buf] + flat));    \
      int vr = flat >> 6, vc = flat & 63;                                         \
      int vsrc = (((vc >> 3) ^ (vr & 7)) << 3) | (vc & 7);                        \
      async16(vb + (size_t)vr * SEQ + (s0_) + vsrc, (void*)(Vs[buf] + flat));     \
    }                                                                             \
  }

  for (int half = 0; half < 2; ++half) {
    int qt = half ? (31 - pp) : pp;
    int q0 = qt * 64;
    int qw = q0 + wave * 16;
    const bf16_t* qbase = q + ((size_t)(b * SEQ + qw + lr)) * DIMSZ + h * HD;
    bf16x8 qf[4];
#pragma unroll
    for (int kk = 0; kk < 4; ++kk) qf[kk] = *(const bf16x8*)(qbase + kk * 32 + lg * 8);
    f32x4 o[8] = {};
    float m_[4], l_[4];
#pragma unroll
    for (int j = 0; j < 4; ++j) { m_[j] = -3.0e38f; l_[j] = 0.f; }
    int qglob0 = qw + lg * 4;
    int ntiles = qt + 1;

    STAGE_TILE(0, 0)
    __syncthreads();
    for (int t = 0; t < ntiles; ++t) {
      int cur = t & 1;
      if (t + 1 < ntiles) STAGE_TILE(cur ^ 1, (t + 1) * 64)
      int s0 = t * 64;
      const bf16_t* Kc = Ks[cur];
      const bf16_t* Vc = Vs[cur];
      f32x4 sf[4] = {};
#pragma unroll
      for (int nf = 0; nf < 4; ++nf) {
        int R = nf * 16 + lr;
#pragma unroll
        for (int kk = 0; kk < 4; ++kk)
          sf[nf] = __builtin_amdgcn_mfma_f32_16x16x32_bf16(
              qf[kk],
              *(const bf16x8*)(Kc + R * 128 + (((kk * 4 + lg) ^ (R & 7)) << 3)),
              sf[nf], 0, 0, 0);
      }
#pragma unroll
      for (int nf = 0; nf < 4; ++nf) {
        int col = s0 + nf * 16 + lr;
#pragma unroll
        for (int j = 0; j < 4; ++j) {
          float v = sf[nf][j] * 0.088388347648318447f;
          sf[nf][j] = (col <= qglob0 + j) ? v : -3.0e38f;
        }
      }
      float mx[4];
#pragma unroll
      for (int j = 0; j < 4; ++j)
        mx[j] = fmaxf(fmaxf(sf[0][j], sf[1][j]), fmaxf(sf[2][j], sf[3][j]));
#pragma unroll
      for (int o_ = 1; o_ < 16; o_ <<= 1)
#pragma unroll
        for (int j = 0; j < 4; ++j) mx[j] = fmaxf(mx[j], __shfl_xor(mx[j], o_));
      float fsc[4], mn[4];
#pragma unroll
      for (int j = 0; j < 4; ++j) {
        mn[j] = fmaxf(m_[j], mx[j]);
        fsc[j] = __expf(m_[j] - mn[j]);
        m_[j] = mn[j];
      }
      float ps[4] = {0.f, 0.f, 0.f, 0.f};
#pragma unroll
      for (int nf = 0; nf < 4; ++nf)
#pragma unroll
        for (int j = 0; j < 4; ++j) {
          float pv = __expf(sf[nf][j] - mn[j]);
          ps[j] += pv;
          Pw[wave][lg * 4 + j][nf * 16 + lr] = (bf16_t)pv;
        }
#pragma unroll
      for (int o_ = 1; o_ < 16; o_ <<= 1)
#pragma unroll
        for (int j = 0; j < 4; ++j) ps[j] += __shfl_xor(ps[j], o_);
#pragma unroll
      for (int j = 0; j < 4; ++j) l_[j] = l_[j] * fsc[j] + ps[j];
#pragma unroll
      for (int df = 0; df < 8; ++df)
#pragma unroll
        for (int j = 0; j < 4; ++j) o[df][j] *= fsc[j];
      asm volatile("" ::: "memory");
      bf16x8 pa[2];
#pragma unroll
      for (int kk = 0; kk < 2; ++kk)
        pa[kk] = *(const bf16x8*)(&Pw[wave][lr][kk * 32 + lg * 8]);
#pragma unroll
      for (int df = 0; df < 8; ++df) {
        int R = df * 16 + lr;
#pragma unroll
        for (int kk = 0; kk < 2; ++kk)
          o[df] = __builtin_amdgcn_mfma_f32_16x16x32_bf16(
              pa[kk],
              *(const bf16x8*)(Vc + R * 64 + (((kk * 4 + lg) ^ (R & 7)) << 3)),
              o[df], 0, 0, 0);
      }
      __syncthreads();
    }
    bf16_t* cb = ctx + ((size_t)(b * SEQ + qw)) * DIMSZ + h * HD;
#pragma unroll
    for (int df = 0; df < 8; ++df)
#pragma unroll
      for (int j = 0; j < 4; ++j)
        cb[(size_t)(lg * 4 + j) * DIMSZ + df * 16 + lr] = (bf16_t)(o[df][j] / l_[j]);
  }
#undef STAGE_TILE
}

extern "C" void kernel_launch(void* const* d_in, const int* in_sizes, int n_in,
                              void* d_out, int out_size, void* d_ws, size_t ws_size,
                              hipStream_t stream) {
  const float* x   = (const float*)d_in[0];
  const float* wq  = (const float*)d_in[2];
  const float* bq  = (const float*)d_in[3];
  const float* wk  = (const float*)d_in[4];
  const float* bk  = (const float*)d_in[5];
  const float* wv  = (const float*)d_in[6];
  const float* bv  = (const float*)d_in[7];
  const float* wo  = (const float*)d_in[8];
  const float* bo  = (const float*)d_in[9];
  const float* g1  = (const float*)d_in[10];
  const float* be1 = (const float*)d_in[11];
  const float* g2  = (const float*)d_in[12];
  const float* be2 = (const float*)d_in[13];
  const float* w1  = (const float*)d_in[14];
  const float* bb1 = (const float*)d_in[15];
  const float* w2  = (const float*)d_in[16];
  const float* bb2 = (const float*)d_in[17];

  float* outx = (float*)d_out;                       // [4096][2048] (also x1 scratch)
  float* outk = outx + (size_t)MROWS * DIMSZ;        // [4096][128]
  float* outv = outk + (size_t)MROWS * HD;           // [4096][128]

  char* p = (char*)d_ws;
  auto alloc = [&](size_t bytes) -> char* {
    char* r = p;
    p += (bytes + 255) & ~(size_t)255;
    return r;
  };
  bf16_t* wqkvT = (bf16_t*)alloc((size_t)NQKV * DIMSZ * 2);   // [2304][2048]
  bf16_t* woT = (bf16_t*)alloc((size_t)DIMSZ * DIMSZ * 2);
  bf16_t* w1T = (bf16_t*)alloc((size_t)FFDIM * DIMSZ * 2);
  bf16_t* w2T = (bf16_t*)alloc((size_t)DIMSZ * FFDIM * 2);
  bf16_t* hb  = (bf16_t*)alloc((size_t)MROWS * DIMSZ * 2);  // h, later ctx
  bf16_t* qb  = (bf16_t*)alloc((size_t)MROWS * DIMSZ * 2);  // q, later h2
  bf16_t* kbf = (bf16_t*)alloc((size_t)MROWS * HD * 2);
  bf16_t* vbf = (bf16_t*)alloc((size_t)MROWS * HD * 2);
  bf16_t* vtb = (bf16_t*)alloc((size_t)BATCH * HD * SEQ * 2);
  bf16_t* f1b = (bf16_t*)alloc((size_t)MROWS * FFDIM * 2);
  (void)ws_size; (void)in_sizes; (void)n_in; (void)out_size;

  dim3 blk(256);
  const int LDSG = 131072;  // all gemm kernels: 128 KiB dynamic
  // weight transposes / bf16 conversion (64x64 tiles, packed writes)
  k_tr64<<<dim3(DIMSZ / 64, DIMSZ / 64), blk, 0, stream>>>(wq, wqkvT, DIMSZ, DIMSZ);
  k_tr64<<<dim3(HD / 64, DIMSZ / 64), blk, 0, stream>>>(wk, wqkvT + (size_t)2048 * DIMSZ, DIMSZ, HD);
  k_tr64<<<dim3(HD / 64, DIMSZ / 64), blk, 0, stream>>>(wv, wqkvT + (size_t)2176 * DIMSZ, DIMSZ, HD);
  k_tr64<<<dim3(DIMSZ / 64, DIMSZ / 64), blk, 0, stream>>>(wo, woT, DIMSZ, DIMSZ);
  k_tr64<<<dim3(FFDIM / 64, DIMSZ / 64), blk, 0, stream>>>(w1, w1T, DIMSZ, FFDIM);
  k_tr64<<<dim3(DIMSZ / 64, FFDIM / 64), blk, 0, stream>>>(w2, w2T, FFDIM, DIMSZ);
  // ln1: x -> h(bf16)
  k_layernorm<<<MROWS, blk, 0, stream>>>(x, g1, be1, hb);
  // fused q,k,v projection (144 blocks)
  k_qkv<<<(MROWS / 256) * (NQKV / 256), 512, LDSG, stream>>>(
      hb, wqkvT, bq, bk, bv, qb, outk, outv, kbf, vbf);
  k_transpose_v<<<dim3(SEQ / 32, HD / 32, BATCH), blk, 0, stream>>>(vbf, vtb);
  // attention -> ctx (reuse hb)
  k_attn<<<dim3(SEQ / 64 / 2, NH, BATCH), blk, 0, stream>>>(qb, kbf, vtb, hb);
  // o-proj + residual -> outx (x1): 256 blocks
  k_oproj<<<(MROWS / 256) * (DIMSZ / 128), 512, LDSG, stream>>>(hb, woT, bo, x, outx);
  // ln2: x1 -> h2 (reuse qb)
  k_layernorm<<<MROWS, blk, 0, stream>>>(outx, g2, be2, qb);
  // ffn1 + exact gelu -> f1b (bf16): 512 blocks
  k_ffn1<<<(MROWS / 256) * (FFDIM / 256), 512, LDSG, stream>>>(qb, w1T, bb1, f1b);
  // ffn2 split-K x2: 256 blocks, atomic accumulate onto outx (holds x1)
  k_ffn2<<<256, 512, LDSG, stream>>>(f1b, w2T, bb2, outx);
}

// Round 9
// 554.279 us; speedup vs baseline: 1.0726x; 1.0119x over previous
//
#include <hip/hip_runtime.h>
#include <stdint.h>

#define DIMSZ 2048
#define HD 128
#define NH 16
#define BATCH 2
#define SEQ 2048
#define MROWS (BATCH*SEQ)   // 4096
#define FFDIM (4*DIMSZ)     // 8192
#define NQKV (DIMSZ + 2*HD) // 2304

typedef float f32x4 __attribute__((ext_vector_type(4)));
typedef __bf16 bf16x8 __attribute__((ext_vector_type(8)));
typedef __bf16 bf16x2 __attribute__((ext_vector_type(2)));
typedef __bf16 bf16_t;

__device__ __forceinline__ void async16(const void* g, void* l) {
  __builtin_amdgcn_global_load_lds(
      (const __attribute__((address_space(1))) void*)(uintptr_t)g,
      (__attribute__((address_space(3))) void*)(uint32_t)(uintptr_t)l,
      16, 0, 0);
}

__device__ __forceinline__ float gelu_f(float x) {
  return 0.5f * x * (1.0f + erff(x * 0.70710678118654752f));
}

__device__ __forceinline__ void hard_barrier() {
  asm volatile("" ::: "memory");
  __builtin_amdgcn_s_barrier();
  asm volatile("" ::: "memory");
}

// ---------------- transpose f32 (R x C) -> bf16 (C x R), 64x64 tiles --------
__global__ __launch_bounds__(256)
void k_tr64(const float* __restrict__ src, bf16_t* __restrict__ dst,
            int R, int C) {
  __shared__ float tile[64][65];
  int c0 = blockIdx.x * 64, r0 = blockIdx.y * 64;
  int lc = threadIdx.x & 63, lrow = threadIdx.x >> 6;
#pragma unroll
  for (int i = 0; i < 64; i += 4)
    tile[lrow + i][lc] = src[(size_t)(r0 + lrow + i) * C + c0 + lc];
  __syncthreads();
  int rp = threadIdx.x & 31, wc = threadIdx.x >> 5;
#pragma unroll
  for (int i = 0; i < 64; i += 8) {
    int c = wc + i;
    bf16x2 pk = {(bf16_t)tile[2 * rp][c], (bf16_t)tile[2 * rp + 1][c]};
    *(bf16x2*)(dst + (size_t)(c0 + c) * R + r0 + 2 * rp) = pk;
  }
}

// ---------------- transpose v bf16 [B*T][128] -> vt [B][128][T] ----------------
__global__ __launch_bounds__(256)
void k_transpose_v(const bf16_t* __restrict__ v, bf16_t* __restrict__ vt) {
  __shared__ bf16_t tile[32][33];
  int b = blockIdx.z;
  int t0 = blockIdx.x * 32, d0 = blockIdx.y * 32;
  int tx = threadIdx.x & 31, ty = threadIdx.x >> 5;
#pragma unroll
  for (int i = 0; i < 32; i += 8)
    tile[ty + i][tx] = v[((size_t)(b * SEQ + t0 + ty + i)) * HD + d0 + tx];
  __syncthreads();
#pragma unroll
  for (int i = 0; i < 32; i += 8)
    vt[((size_t)(b * HD + d0 + ty + i)) * SEQ + t0 + tx] = tile[tx][ty + i];
}

// ---------------- layernorm f32 -> bf16 ----------------
__global__ __launch_bounds__(256)
void k_layernorm(const float* __restrict__ x, const float* __restrict__ g,
                 const float* __restrict__ bb, bf16_t* __restrict__ out) {
  int row = blockIdx.x;
  const float* xr = x + (size_t)row * DIMSZ;
  int t = threadIdx.x;
  float vals[8];
  float s = 0.f, s2 = 0.f;
#pragma unroll
  for (int i = 0; i < 8; ++i) {
    float v = xr[t + i * 256];
    vals[i] = v; s += v; s2 += v * v;
  }
#pragma unroll
  for (int o = 1; o < 64; o <<= 1) { s += __shfl_xor(s, o); s2 += __shfl_xor(s2, o); }
  __shared__ float red[8];
  if ((t & 63) == 0) { red[t >> 6] = s; red[4 + (t >> 6)] = s2; }
  __syncthreads();
  s = red[0] + red[1] + red[2] + red[3];
  s2 = red[4] + red[5] + red[6] + red[7];
  float mu = s * (1.0f / DIMSZ);
  float rstd = rsqrtf(s2 * (1.0f / DIMSZ) - mu * mu + 1e-5f);
  bf16_t* orow = out + (size_t)row * DIMSZ;
#pragma unroll
  for (int i = 0; i < 8; ++i) {
    int c = t + i * 256;
    orow[c] = (bf16_t)((vals[i] - mu) * rstd * g[c] + bb[c]);
  }
}

// =====================================================================
// 8-phase 256xBN GEMM main loop (verified schedule — unchanged).
// NOTE on block->tile mapping: natural bid%8 XCD round-robin already
// partitions bn mod 8 per XCD when nt%8==0 (B-panels L2-exclusive,
// A via L3). Do NOT chunk-swizzle these grids (r8: FETCH 99->271 MB).
// =====================================================================
template <int FN>
__device__ __forceinline__ void gemm8_loop(
    const bf16_t* __restrict__ A, const bf16_t* __restrict__ BT,
    int ld, int Kloop, int bm, int bn, f32x4 (&acc)[8][FN], bf16_t* sh) {
  constexpr int BH = FN >> 1;
  constexpr int BN = FN * 64;
  const int tid = threadIdx.x;
  const int lane = tid & 63, lr = lane & 15, lg = lane >> 4;
  const int wave = tid >> 6, wm = wave >> 2, wn = wave & 3;
  bf16_t* const Ab0 = sh;            // [(c*2+h)*8192]
  bf16_t* const Bb0 = sh + 32768;    // [(c*BH+h)*8192]
  const bf16_t* const Ag = A + (size_t)bm * 256 * ld;
  const bf16_t* const Bg = BT + (size_t)bn * BN * ld;

  auto stage = [&](const bf16_t* gbase, bf16_t* lbase, int h, int t) {
#pragma unroll
    for (int j = 0; j < 2; ++j) {
      int flat = (tid + j * 512) * 8;
      int r = flat >> 6, kp = flat & 63;
      int ks = kp ^ ((r & 7) << 3);
      async16(gbase + (size_t)(h * 128 + r) * ld + t * 64 + ks, lbase + flat);
    }
  };
  auto stA = [&](int c, int h, int t) { stage(Ag, Ab0 + (c * 2 + h) * 8192, h, t); };
  auto stB = [&](int c, int h, int t) { stage(Bg, Bb0 + (c * BH + h) * 8192, h, t); };

  const int xsw = (lr & 7) << 3;
  bf16x8 a_[8], b_[FN][2];
  auto lda = [&](int c, int kk) {
    const bf16_t* base = Ab0 + (c * 2 + wm) * 8192;
#pragma unroll
    for (int mf = 0; mf < 8; ++mf)
      a_[mf] = *(const bf16x8*)(base + (mf * 16 + lr) * 64 + ((kk + lg * 8) ^ xsw));
  };
  auto ldb = [&](int c) {
#pragma unroll
    for (int nf = 0; nf < FN; ++nf) {
      int row = wn * (FN * 16) + nf * 16 + lr;
      const bf16_t* base =
          Bb0 + (c * BH + (BH == 2 ? (row >> 7) : 0)) * 8192 + (row & 127) * 64;
#pragma unroll
      for (int kx = 0; kx < 2; ++kx)
        b_[nf][kx] = *(const bf16x8*)(base + ((kx * 32 + lg * 8) ^ xsw));
    }
  };

#define LGKM0 asm volatile("s_waitcnt lgkmcnt(0)" ::: "memory");
#define VMC_STEADY                                                   \
  if (BH == 2) { asm volatile("s_waitcnt vmcnt(6)" ::: "memory"); }  \
  else         { asm volatile("s_waitcnt vmcnt(4)" ::: "memory"); }
#define MFMA_HALF(M0, KX)                                            \
  __builtin_amdgcn_s_setprio(1);                                     \
  _Pragma("unroll")                                                  \
  for (int mf = 0; mf < 4; ++mf)                                     \
    _Pragma("unroll")                                                \
    for (int nf = 0; nf < FN; ++nf)                                  \
      acc[(M0) + mf][nf] = __builtin_amdgcn_mfma_f32_16x16x32_bf16(  \
          a_[(M0) + mf], b_[nf][KX], acc[(M0) + mf][nf], 0, 0, 0);   \
  __builtin_amdgcn_s_setprio(0);

  const int nit = Kloop >> 7;

  stA(0, 0, 0); stA(0, 1, 0);
  stB(0, 0, 0); if (BH == 2) stB(0, 1, 0);
  stB(1, 0, 1); if (BH == 2) stB(1, 1, 1);
  stA(1, 0, 1);
  VMC_STEADY;
  hard_barrier();

  for (int i = 0; i < nit; ++i) {
    const int t1 = 2 * i + 1, t2 = 2 * i + 2, t3 = 2 * i + 3;
    const bool g2 = (i < nit - 1);
    // ---- P1 ----
    lda(0, 0); ldb(0);
    stA(1, 1, t1);
    hard_barrier(); LGKM0;
    MFMA_HALF(0, 0)
    hard_barrier();
    // ---- P2 ----
    if (g2) stB(0, 0, t2);
    hard_barrier();
    MFMA_HALF(4, 0)
    hard_barrier();
    // ---- P3 ----
    lda(0, 32);
    if (g2 && BH == 2) stB(0, 1, t2);
    hard_barrier(); LGKM0;
    MFMA_HALF(0, 1)
    hard_barrier();
    // ---- P4 ----
    if (g2) stA(0, 0, t2);
    if (i == nit - 1) { asm volatile("s_waitcnt vmcnt(0)" ::: "memory"); }
    else { VMC_STEADY; }
    hard_barrier();
    MFMA_HALF(4, 1)
    hard_barrier();
    // ---- P5 ----
    lda(1, 0); ldb(1);
    if (g2) stA(0, 1, t2);
    hard_barrier(); LGKM0;
    MFMA_HALF(0, 0)
    hard_barrier();
    // ---- P6 ----
    if (g2) stB(1, 0, t3);
    hard_barrier();
    MFMA_HALF(4, 0)
    hard_barrier();
    // ---- P7 ----
    lda(1, 32);
    if (g2 && BH == 2) stB(1, 1, t3);
    hard_barrier(); LGKM0;
    MFMA_HALF(0, 1)
    hard_barrier();
    // ---- P8 ----
    if (g2) {
      stA(1, 0, t3);
      VMC_STEADY;
    }
    hard_barrier();
    MFMA_HALF(4, 1)
    hard_barrier();
  }
#undef LGKM0
#undef VMC_STEADY
#undef MFMA_HALF
}

// ---------------- o-proj: FN=2, out = acc + bo + x (f32), restaged ----------
__global__ __launch_bounds__(512, 1)
void k_oproj(const bf16_t* __restrict__ A, const bf16_t* __restrict__ BT,
             const float* __restrict__ bias, const float* __restrict__ res,
             float* __restrict__ outF) {
  extern __shared__ __align__(16) bf16_t sh8[];
  const int nt = DIMSZ / 128;  // 16
  int bm = blockIdx.x / nt, bn = blockIdx.x % nt;   // natural mapping
  f32x4 acc[8][2] = {};
  gemm8_loop<2>(A, BT, DIMSZ, DIMSZ, bm, bn, acc, sh8);
  int tid = threadIdx.x, wave = tid >> 6, lane = tid & 63, lr = lane & 15, lg = lane >> 4;
  int wm = wave >> 2, wn = wave & 3;
  // phase A: acc+bias -> LDS f32 [256][128]
  float* shF = (float*)sh8;
  int rl0 = wm * 128 + lg * 4;
  int cl0 = wn * 32 + lr;
#pragma unroll
  for (int nf = 0; nf < 2; ++nf) {
    int cl = cl0 + nf * 16;
    float bi = bias[bn * 128 + cl];
#pragma unroll
    for (int mf = 0; mf < 8; ++mf)
#pragma unroll
      for (int j = 0; j < 4; ++j)
        shF[(rl0 + mf * 16 + j) * 128 + cl] = acc[mf][nf][j] + bi;
  }
  hard_barrier();
  // phase B: coalesced +res -> outF
  const float* rbase = res + (size_t)(bm * 256) * DIMSZ + bn * 128;
  float* gbase = outF + (size_t)(bm * 256) * DIMSZ + bn * 128;
#pragma unroll
  for (int s = 0; s < 16; ++s) {
    int flat = s * 512 + tid;           // 16B units
    int row = flat >> 5, cu = flat & 31;  // 32 units per 128-f32 row
    f32x4 v = *(const f32x4*)(shF + row * 128 + cu * 4);
    f32x4 r4 = *(const f32x4*)(rbase + (size_t)row * DIMSZ + cu * 4);
    *(f32x4*)(gbase + (size_t)row * DIMSZ + cu * 4) = v + r4;
  }
}

// ---------------- ffn1: FN=4, out = gelu(acc + b1) bf16, restaged -----------
__global__ __launch_bounds__(512, 1)
void k_ffn1(const bf16_t* __restrict__ A, const bf16_t* __restrict__ BT,
            const float* __restrict__ bias, bf16_t* __restrict__ outB) {
  extern __shared__ __align__(16) bf16_t sh8[];
  const int nt = FFDIM / 256;  // 32
  int bm = blockIdx.x / nt, bn = blockIdx.x % nt;   // natural mapping
  f32x4 acc[8][4] = {};
  gemm8_loop<4>(A, BT, DIMSZ, DIMSZ, bm, bn, acc, sh8);
  int tid = threadIdx.x, wave = tid >> 6, lane = tid & 63, lr = lane & 15, lg = lane >> 4;
  int wm = wave >> 2, wn = wave & 3;
  // phase A: gelu(acc+bias) -> LDS bf16 [256][256]
  int rl0 = wm * 128 + lg * 4;
  int cl0 = wn * 64 + lr;
#pragma unroll
  for (int nf = 0; nf < 4; ++nf) {
    int cl = cl0 + nf * 16;
    float bi = bias[bn * 256 + cl];
#pragma unroll
    for (int mf = 0; mf < 8; ++mf)
#pragma unroll
      for (int j = 0; j < 4; ++j)
        sh8[(rl0 + mf * 16 + j) * 256 + cl] = (bf16_t)gelu_f(acc[mf][nf][j] + bi);
  }
  hard_barrier();
  // phase B: coalesced copy LDS -> outB
  bf16_t* gbase = outB + (size_t)(bm * 256) * FFDIM + bn * 256;
#pragma unroll
  for (int s = 0; s < 16; ++s) {
    int flat = s * 512 + tid;             // 16B units
    int row = flat >> 5, cu = flat & 31;  // 32 units per 256-bf16 row
    f32x4 v = *(const f32x4*)(sh8 + row * 256 + cu * 8);
    *(f32x4*)(gbase + (size_t)row * FFDIM + cu * 8) = v;
  }
}

// ---------------- ffn2: FN=4 split-K x2, atomic accumulate ----------------
// Keeps the chunked mapping (r8): per-XCD 2D regions (4bm x 8bn, kh pairs)
// gave ideal FETCH (~98 MB); natural mapping would broadcast A to all 8 XCDs.
__global__ __launch_bounds__(512, 1)
void k_ffn2(const bf16_t* __restrict__ A, const bf16_t* __restrict__ BT,
            const float* __restrict__ bias, float* __restrict__ outF) {
  extern __shared__ __align__(16) bf16_t sh8[];
  int swz = (blockIdx.x & 7) * 32 + (blockIdx.x >> 3);
  int kh = swz >> 7;
  int tile = swz & 127;
  int bm = tile >> 3, bn = tile & 7;   // 16 x 8
  f32x4 acc[8][4] = {};
  gemm8_loop<4>(A + kh * (FFDIM / 2), BT + kh * (FFDIM / 2), FFDIM, FFDIM / 2,
                bm, bn, acc, sh8);
  int tid = threadIdx.x, wave = tid >> 6, lane = tid & 63, lr = lane & 15, lg = lane >> 4;
  int wm = wave >> 2, wn = wave & 3;
  int row0 = bm * 256 + wm * 128 + lg * 4;
  int col0 = bn * 256 + wn * 64 + lr;
#pragma unroll
  for (int nf = 0; nf < 4; ++nf) {
    int c = col0 + nf * 16;
    float bi = kh ? 0.f : bias[c];
#pragma unroll
    for (int mf = 0; mf < 8; ++mf)
#pragma unroll
      for (int j = 0; j < 4; ++j) {
        int r = row0 + mf * 16 + j;
        __hip_atomic_fetch_add(&outF[(size_t)r * DIMSZ + c], acc[mf][nf][j] + bi,
                               __ATOMIC_RELAXED, __HIP_MEMORY_SCOPE_AGENT);
      }
  }
}

// ---------------- fused QKV: N = 2304 (2048 q | 128 k | 128 v), restaged ----
__global__ __launch_bounds__(512, 1)
void k_qkv(const bf16_t* __restrict__ A, const bf16_t* __restrict__ BT,
           const float* __restrict__ bq, const float* __restrict__ bk,
           const float* __restrict__ bv,
           bf16_t* __restrict__ qb, float* __restrict__ outk,
           float* __restrict__ outv, bf16_t* __restrict__ kbf,
           bf16_t* __restrict__ vbf) {
  extern __shared__ __align__(16) bf16_t sh8[];
  const int nt = NQKV / 256;  // 9
  int bm = blockIdx.x / nt, bn = blockIdx.x % nt;   // natural mapping
  f32x4 acc[8][4] = {};
  gemm8_loop<4>(A, BT, DIMSZ, DIMSZ, bm, bn, acc, sh8);
  int tid = threadIdx.x, wave = tid >> 6, lane = tid & 63, lr = lane & 15, lg = lane >> 4;
  int wm = wave >> 2, wn = wave & 3;
  // phase A: acc+bias -> LDS bf16 [256][256]; f32 k/v copies stored directly
  int rl0 = wm * 128 + lg * 4;
  int cl0 = wn * 64 + lr;
#pragma unroll
  for (int nf = 0; nf < 4; ++nf) {
    int cl = cl0 + nf * 16;
    int cg = bn * 256 + cl;
    float bi = (cg < 2048) ? bq[cg] : (cg < 2176 ? bk[cg - 2048] : bv[cg - 2176]);
#pragma unroll
    for (int mf = 0; mf < 8; ++mf)
#pragma unroll
      for (int j = 0; j < 4; ++j) {
        float v = acc[mf][nf][j] + bi;
        sh8[(rl0 + mf * 16 + j) * 256 + cl] = (bf16_t)v;
        if (cg >= 2048) {
          int r = bm * 256 + rl0 + mf * 16 + j;
          if (cg < 2176) outk[(size_t)r * HD + (cg - 2048)] = v;
          else           outv[(size_t)r * HD + (cg - 2176)] = v;
        }
      }
  }
  hard_barrier();
  // phase B: coalesced LDS -> qb or kbf/vbf
#pragma unroll
  for (int s = 0; s < 16; ++s) {
    int flat = s * 512 + tid;
    int row = flat >> 5, cu = flat & 31;
    f32x4 v = *(const f32x4*)(sh8 + row * 256 + cu * 8);
    int r = bm * 256 + row;
    if (bn < 8) {
      *(f32x4*)(qb + (size_t)r * DIMSZ + bn * 256 + cu * 8) = v;
    } else {
      int ce = cu * 8;  // 0..255
      if (ce < 128) *(f32x4*)(kbf + (size_t)r * HD + ce) = v;
      else          *(f32x4*)(vbf + (size_t)r * HD + (ce - 128)) = v;
    }
  }
}

// ---------------- causal flash attention (MQA) ----------------
__global__ __launch_bounds__(256, 2)
void k_attn(const bf16_t* __restrict__ q, const bf16_t* __restrict__ k,
            const bf16_t* __restrict__ vt, bf16_t* __restrict__ ctx) {
  __shared__ __align__(16) bf16_t Ks[2][64 * 128];
  __shared__ __align__(16) bf16_t Vs[2][128 * 64];
  __shared__ bf16_t Pw[4][16][72];
  int pp = blockIdx.x, h = blockIdx.y, b = blockIdx.z;
  int tid = threadIdx.x, wave = tid >> 6, lane = tid & 63, lr = lane & 15, lg = lane >> 4;
  const bf16_t* kb = k + (size_t)b * SEQ * HD;
  const bf16_t* vb = vt + (size_t)b * HD * SEQ;

#define STAGE_TILE(buf, s0_)                                                      \
  {                                                                               \
    _Pragma("unroll")                                                             \
    for (int i = 0; i < 4; ++i) {                                                 \
      int flat = (i * 256 + tid) * 8;                                             \
      int kr = flat >> 7, kc = flat & 127;                                        \
      int ksrc = (((kc >> 3) ^ (kr & 7)) << 3) | (kc & 7);                        \
      async16(kb + (size_t)((s0_) + kr) * HD + ksrc, (void*)(Ks[buf] + flat));    \
      int vr = flat >> 6, vc = flat & 63;                                         \
      int vsrc = (((vc >> 3) ^ (vr & 7)) << 3) | (vc & 7);                        \
      async16(vb + (size_t)vr * SEQ + (s0_) + vsrc, (void*)(Vs[buf] + flat));     \
    }                                                                             \
  }

  for (int half = 0; half < 2; ++half) {
    int qt = half ? (31 - pp) : pp;
    int q0 = qt * 64;
    int qw = q0 + wave * 16;
    const bf16_t* qbase = q + ((size_t)(b * SEQ + qw + lr)) * DIMSZ + h * HD;
    bf16x8 qf[4];
#pragma unroll
    for (int kk = 0; kk < 4; ++kk) qf[kk] = *(const bf16x8*)(qbase + kk * 32 + lg * 8);
    f32x4 o[8] = {};
    float m_[4], l_[4];
#pragma unroll
    for (int j = 0; j < 4; ++j) { m_[j] = -3.0e38f; l_[j] = 0.f; }
    int qglob0 = qw + lg * 4;
    int ntiles = qt + 1;

    STAGE_TILE(0, 0)
    __syncthreads();
    for (int t = 0; t < ntiles; ++t) {
      int cur = t & 1;
      if (t + 1 < ntiles) STAGE_TILE(cur ^ 1, (t + 1) * 64)
      int s0 = t * 64;
      const bf16_t* Kc = Ks[cur];
      const bf16_t* Vc = Vs[cur];
      f32x4 sf[4] = {};
#pragma unroll
      for (int nf = 0; nf < 4; ++nf) {
        int R = nf * 16 + lr;
#pragma unroll
        for (int kk = 0; kk < 4; ++kk)
          sf[nf] = __builtin_amdgcn_mfma_f32_16x16x32_bf16(
              qf[kk],
              *(const bf16x8*)(Kc + R * 128 + (((kk * 4 + lg) ^ (R & 7)) << 3)),
              sf[nf], 0, 0, 0);
      }
#pragma unroll
      for (int nf = 0; nf < 4; ++nf) {
        int col = s0 + nf * 16 + lr;
#pragma unroll
        for (int j = 0; j < 4; ++j) {
          float v = sf[nf][j] * 0.088388347648318447f;
          sf[nf][j] = (col <= qglob0 + j) ? v : -3.0e38f;
        }
      }
      float mx[4];
#pragma unroll
      for (int j = 0; j < 4; ++j)
        mx[j] = fmaxf(fmaxf(sf[0][j], sf[1][j]), fmaxf(sf[2][j], sf[3][j]));
#pragma unroll
      for (int o_ = 1; o_ < 16; o_ <<= 1)
#pragma unroll
        for (int j = 0; j < 4; ++j) mx[j] = fmaxf(mx[j], __shfl_xor(mx[j], o_));
      float fsc[4], mn[4];
#pragma unroll
      for (int j = 0; j < 4; ++j) {
        mn[j] = fmaxf(m_[j], mx[j]);
        fsc[j] = __expf(m_[j] - mn[j]);
        m_[j] = mn[j];
      }
      float ps[4] = {0.f, 0.f, 0.f, 0.f};
#pragma unroll
      for (int nf = 0; nf < 4; ++nf)
#pragma unroll
        for (int j = 0; j < 4; ++j) {
          float pv = __expf(sf[nf][j] - mn[j]);
          ps[j] += pv;
          Pw[wave][lg * 4 + j][nf * 16 + lr] = (bf16_t)pv;
        }
#pragma unroll
      for (int o_ = 1; o_ < 16; o_ <<= 1)
#pragma unroll
        for (int j = 0; j < 4; ++j) ps[j] += __shfl_xor(ps[j], o_);
#pragma unroll
      for (int j = 0; j < 4; ++j) l_[j] = l_[j] * fsc[j] + ps[j];
#pragma unroll
      for (int df = 0; df < 8; ++df)
#pragma unroll
        for (int j = 0; j < 4; ++j) o[df][j] *= fsc[j];
      asm volatile("" ::: "memory");
      bf16x8 pa[2];
#pragma unroll
      for (int kk = 0; kk < 2; ++kk)
        pa[kk] = *(const bf16x8*)(&Pw[wave][lr][kk * 32 + lg * 8]);
#pragma unroll
      for (int df = 0; df < 8; ++df) {
        int R = df * 16 + lr;
#pragma unroll
        for (int kk = 0; kk < 2; ++kk)
          o[df] = __builtin_amdgcn_mfma_f32_16x16x32_bf16(
              pa[kk],
              *(const bf16x8*)(Vc + R * 64 + (((kk * 4 + lg) ^ (R & 7)) << 3)),
              o[df], 0, 0, 0);
      }
      __syncthreads();
    }
    bf16_t* cb = ctx + ((size_t)(b * SEQ + qw)) * DIMSZ + h * HD;
#pragma unroll
    for (int df = 0; df < 8; ++df)
#pragma unroll
      for (int j = 0; j < 4; ++j)
        cb[(size_t)(lg * 4 + j) * DIMSZ + df * 16 + lr] = (bf16_t)(o[df][j] / l_[j]);
  }
#undef STAGE_TILE
}

extern "C" void kernel_launch(void* const* d_in, const int* in_sizes, int n_in,
                              void* d_out, int out_size, void* d_ws, size_t ws_size,
                              hipStream_t stream) {
  const float* x   = (const float*)d_in[0];
  const float* wq  = (const float*)d_in[2];
  const float* bq  = (const float*)d_in[3];
  const float* wk  = (const float*)d_in[4];
  const float* bk  = (const float*)d_in[5];
  const float* wv  = (const float*)d_in[6];
  const float* bv  = (const float*)d_in[7];
  const float* wo  = (const float*)d_in[8];
  const float* bo  = (const float*)d_in[9];
  const float* g1  = (const float*)d_in[10];
  const float* be1 = (const float*)d_in[11];
  const float* g2  = (const float*)d_in[12];
  const float* be2 = (const float*)d_in[13];
  const float* w1  = (const float*)d_in[14];
  const float* bb1 = (const float*)d_in[15];
  const float* w2  = (const float*)d_in[16];
  const float* bb2 = (const float*)d_in[17];

  float* outx = (float*)d_out;                       // [4096][2048] (also x1 scratch)
  float* outk = outx + (size_t)MROWS * DIMSZ;        // [4096][128]
  float* outv = outk + (size_t)MROWS * HD;           // [4096][128]

  char* p = (char*)d_ws;
  auto alloc = [&](size_t bytes) -> char* {
    char* r = p;
    p += (bytes + 255) & ~(size_t)255;
    return r;
  };
  bf16_t* wqkvT = (bf16_t*)alloc((size_t)NQKV * DIMSZ * 2);   // [2304][2048]
  bf16_t* woT = (bf16_t*)alloc((size_t)DIMSZ * DIMSZ * 2);
  bf16_t* w1T = (bf16_t*)alloc((size_t)FFDIM * DIMSZ * 2);
  bf16_t* w2T = (bf16_t*)alloc((size_t)DIMSZ * FFDIM * 2);
  bf16_t* hb  = (bf16_t*)alloc((size_t)MROWS * DIMSZ * 2);  // h, later ctx
  bf16_t* qb  = (bf16_t*)alloc((size_t)MROWS * DIMSZ * 2);  // q, later h2
  bf16_t* kbf = (bf16_t*)alloc((size_t)MROWS * HD * 2);
  bf16_t* vbf = (bf16_t*)alloc((size_t)MROWS * HD * 2);
  bf16_t* vtb = (bf16_t*)alloc((size_t)BATCH * HD * SEQ * 2);
  bf16_t* f1b = (bf16_t*)alloc((size_t)MROWS * FFDIM * 2);
  (void)ws_size; (void)in_sizes; (void)n_in; (void)out_size;

  dim3 blk(256);
  const int LDSG = 131072;  // all gemm kernels: 128 KiB dynamic
  // weight transposes / bf16 conversion (64x64 tiles, packed writes)
  k_tr64<<<dim3(DIMSZ / 64, DIMSZ / 64), blk, 0, stream>>>(wq, wqkvT, DIMSZ, DIMSZ);
  k_tr64<<<dim3(HD / 64, DIMSZ / 64), blk, 0, stream>>>(wk, wqkvT + (size_t)2048 * DIMSZ, DIMSZ, HD);
  k_tr64<<<dim3(HD / 64, DIMSZ / 64), blk, 0, stream>>>(wv, wqkvT + (size_t)2176 * DIMSZ, DIMSZ, HD);
  k_tr64<<<dim3(DIMSZ / 64, DIMSZ / 64), blk, 0, stream>>>(wo, woT, DIMSZ, DIMSZ);
  k_tr64<<<dim3(FFDIM / 64, DIMSZ / 64), blk, 0, stream>>>(w1, w1T, DIMSZ, FFDIM);
  k_tr64<<<dim3(DIMSZ / 64, FFDIM / 64), blk, 0, stream>>>(w2, w2T, FFDIM, DIMSZ);
  // ln1: x -> h(bf16)
  k_layernorm<<<MROWS, blk, 0, stream>>>(x, g1, be1, hb);
  // fused q,k,v projection (144 blocks)
  k_qkv<<<(MROWS / 256) * (NQKV / 256), 512, LDSG, stream>>>(
      hb, wqkvT, bq, bk, bv, qb, outk, outv, kbf, vbf);
  k_transpose_v<<<dim3(SEQ / 32, HD / 32, BATCH), blk, 0, stream>>>(vbf, vtb);
  // attention -> ctx (reuse hb)
  k_attn<<<dim3(SEQ / 64 / 2, NH, BATCH), blk, 0, stream>>>(qb, kbf, vtb, hb);
  // o-proj + residual -> outx (x1): 256 blocks
  k_oproj<<<(MROWS / 256) * (DIMSZ / 128), 512, LDSG, stream>>>(hb, woT, bo, x, outx);
  // ln2: x1 -> h2 (reuse qb)
  k_layernorm<<<MROWS, blk, 0, stream>>>(outx, g2, be2, qb);
  // ffn1 + exact gelu -> f1b (bf16): 512 blocks
  k_ffn1<<<(MROWS / 256) * (FFDIM / 256), 512, LDSG, stream>>>(qb, w1T, bb1, f1b);
  // ffn2 split-K x2: 256 blocks, atomic accumulate onto outx (holds x1)
  k_ffn2<<<256, 512, LDSG, stream>>>(f1b, w2T, bb2, outx);
}

// Round 10
// 522.752 us; speedup vs baseline: 1.1373x; 1.0603x over previous
//
#include <hip/hip_runtime.h>
#include <stdint.h>

#define DIMSZ 2048
#define HD 128
#define NH 16
#define BATCH 2
#define SEQ 2048
#define MROWS (BATCH*SEQ)   // 4096
#define FFDIM (4*DIMSZ)     // 8192
#define NQKV (DIMSZ + 2*HD) // 2304

typedef float f32x4 __attribute__((ext_vector_type(4)));
typedef __bf16 bf16x8 __attribute__((ext_vector_type(8)));
typedef __bf16 bf16x2 __attribute__((ext_vector_type(2)));
typedef _Float16 f16x8 __attribute__((ext_vector_type(8)));
typedef __bf16 bf16_t;
typedef _Float16 f16_t;

__device__ __forceinline__ void async16(const void* g, void* l) {
  __builtin_amdgcn_global_load_lds(
      (const __attribute__((address_space(1))) void*)(uintptr_t)g,
      (__attribute__((address_space(3))) void*)(uint32_t)(uintptr_t)l,
      16, 0, 0);
}

__device__ __forceinline__ float gelu_f(float x) {
  return 0.5f * x * (1.0f + erff(x * 0.70710678118654752f));
}

__device__ __forceinline__ void hard_barrier() {
  asm volatile("" ::: "memory");
  __builtin_amdgcn_s_barrier();
  asm volatile("" ::: "memory");
}

// ---------------- all weight transposes in ONE launch ----------------
// f32 (R x C) -> bf16 (C x R), 64x64 tiles; job decoded from blockIdx.
__global__ __launch_bounds__(256)
void k_trall(const float* __restrict__ wq, const float* __restrict__ wk,
             const float* __restrict__ wv, const float* __restrict__ wo,
             const float* __restrict__ w1, const float* __restrict__ w2,
             bf16_t* __restrict__ wqkvT, bf16_t* __restrict__ woT,
             bf16_t* __restrict__ w1T, bf16_t* __restrict__ w2T) {
  int bid = blockIdx.x;
  const float* src; bf16_t* dst; int R, C, t0;
  if (bid < 1024)      { src = wq; dst = wqkvT;                        R = 2048; C = 2048; t0 = bid; }
  else if (bid < 1088) { src = wk; dst = wqkvT + (size_t)2048 * 2048;  R = 2048; C = 128;  t0 = bid - 1024; }
  else if (bid < 1152) { src = wv; dst = wqkvT + (size_t)2176 * 2048;  R = 2048; C = 128;  t0 = bid - 1088; }
  else if (bid < 2176) { src = wo; dst = woT;                          R = 2048; C = 2048; t0 = bid - 1152; }
  else if (bid < 6272) { src = w1; dst = w1T;                          R = 2048; C = 8192; t0 = bid - 2176; }
  else                 { src = w2; dst = w2T;                          R = 8192; C = 2048; t0 = bid - 6272; }
  int tc = C >> 6;
  int c0 = (t0 % tc) * 64, r0 = (t0 / tc) * 64;
  __shared__ float tile[64][65];
  int lc = threadIdx.x & 63, lrow = threadIdx.x >> 6;
#pragma unroll
  for (int i = 0; i < 64; i += 4)
    tile[lrow + i][lc] = src[(size_t)(r0 + lrow + i) * C + c0 + lc];
  __syncthreads();
  int rp = threadIdx.x & 31, wc = threadIdx.x >> 5;
#pragma unroll
  for (int i = 0; i < 64; i += 8) {
    int c = wc + i;
    bf16x2 pk = {(bf16_t)tile[2 * rp][c], (bf16_t)tile[2 * rp + 1][c]};
    *(bf16x2*)(dst + (size_t)(c0 + c) * R + r0 + 2 * rp) = pk;
  }
}

// ---------------- transpose v bf16 [B*T][128] -> vt [B][128][T] ----------------
__global__ __launch_bounds__(256)
void k_transpose_v(const bf16_t* __restrict__ v, bf16_t* __restrict__ vt) {
  __shared__ bf16_t tile[32][33];
  int b = blockIdx.z;
  int t0 = blockIdx.x * 32, d0 = blockIdx.y * 32;
  int tx = threadIdx.x & 31, ty = threadIdx.x >> 5;
#pragma unroll
  for (int i = 0; i < 32; i += 8)
    tile[ty + i][tx] = v[((size_t)(b * SEQ + t0 + ty + i)) * HD + d0 + tx];
  __syncthreads();
#pragma unroll
  for (int i = 0; i < 32; i += 8)
    vt[((size_t)(b * HD + d0 + ty + i)) * SEQ + t0 + tx] = tile[tx][ty + i];
}

// ---------------- layernorm f32 -> bf16 ----------------
__global__ __launch_bounds__(256)
void k_layernorm(const float* __restrict__ x, const float* __restrict__ g,
                 const float* __restrict__ bb, bf16_t* __restrict__ out) {
  int row = blockIdx.x;
  const float* xr = x + (size_t)row * DIMSZ;
  int t = threadIdx.x;
  float vals[8];
  float s = 0.f, s2 = 0.f;
#pragma unroll
  for (int i = 0; i < 8; ++i) {
    float v = xr[t + i * 256];
    vals[i] = v; s += v; s2 += v * v;
  }
#pragma unroll
  for (int o = 1; o < 64; o <<= 1) { s += __shfl_xor(s, o); s2 += __shfl_xor(s2, o); }
  __shared__ float red[8];
  if ((t & 63) == 0) { red[t >> 6] = s; red[4 + (t >> 6)] = s2; }
  __syncthreads();
  s = red[0] + red[1] + red[2] + red[3];
  s2 = red[4] + red[5] + red[6] + red[7];
  float mu = s * (1.0f / DIMSZ);
  float rstd = rsqrtf(s2 * (1.0f / DIMSZ) - mu * mu + 1e-5f);
  bf16_t* orow = out + (size_t)row * DIMSZ;
#pragma unroll
  for (int i = 0; i < 8; ++i) {
    int c = t + i * 256;
    orow[c] = (bf16_t)((vals[i] - mu) * rstd * g[c] + bb[c]);
  }
}

// =====================================================================
// 8-phase 256xBN GEMM main loop (verified schedule — unchanged).
// NOTE: natural bid%8 XCD round-robin partitions bn mod 8 per XCD when
// nt%8==0 (B-panels L2-exclusive). Do NOT chunk-swizzle (r8: FETCH 3x).
// =====================================================================
template <int FN>
__device__ __forceinline__ void gemm8_loop(
    const bf16_t* __restrict__ A, const bf16_t* __restrict__ BT,
    int ld, int Kloop, int bm, int bn, f32x4 (&acc)[8][FN], bf16_t* sh) {
  constexpr int BH = FN >> 1;
  constexpr int BN = FN * 64;
  const int tid = threadIdx.x;
  const int lane = tid & 63, lr = lane & 15, lg = lane >> 4;
  const int wave = tid >> 6, wm = wave >> 2, wn = wave & 3;
  bf16_t* const Ab0 = sh;            // [(c*2+h)*8192]
  bf16_t* const Bb0 = sh + 32768;    // [(c*BH+h)*8192]
  const bf16_t* const Ag = A + (size_t)bm * 256 * ld;
  const bf16_t* const Bg = BT + (size_t)bn * BN * ld;

  auto stage = [&](const bf16_t* gbase, bf16_t* lbase, int h, int t) {
#pragma unroll
    for (int j = 0; j < 2; ++j) {
      int flat = (tid + j * 512) * 8;
      int r = flat >> 6, kp = flat & 63;
      int ks = kp ^ ((r & 7) << 3);
      async16(gbase + (size_t)(h * 128 + r) * ld + t * 64 + ks, lbase + flat);
    }
  };
  auto stA = [&](int c, int h, int t) { stage(Ag, Ab0 + (c * 2 + h) * 8192, h, t); };
  auto stB = [&](int c, int h, int t) { stage(Bg, Bb0 + (c * BH + h) * 8192, h, t); };

  const int xsw = (lr & 7) << 3;
  bf16x8 a_[8], b_[FN][2];
  auto lda = [&](int c, int kk) {
    const bf16_t* base = Ab0 + (c * 2 + wm) * 8192;
#pragma unroll
    for (int mf = 0; mf < 8; ++mf)
      a_[mf] = *(const bf16x8*)(base + (mf * 16 + lr) * 64 + ((kk + lg * 8) ^ xsw));
  };
  auto ldb = [&](int c) {
#pragma unroll
    for (int nf = 0; nf < FN; ++nf) {
      int row = wn * (FN * 16) + nf * 16 + lr;
      const bf16_t* base =
          Bb0 + (c * BH + (BH == 2 ? (row >> 7) : 0)) * 8192 + (row & 127) * 64;
#pragma unroll
      for (int kx = 0; kx < 2; ++kx)
        b_[nf][kx] = *(const bf16x8*)(base + ((kx * 32 + lg * 8) ^ xsw));
    }
  };

#define LGKM0 asm volatile("s_waitcnt lgkmcnt(0)" ::: "memory");
#define VMC_STEADY                                                   \
  if (BH == 2) { asm volatile("s_waitcnt vmcnt(6)" ::: "memory"); }  \
  else         { asm volatile("s_waitcnt vmcnt(4)" ::: "memory"); }
#define MFMA_HALF(M0, KX)                                            \
  __builtin_amdgcn_s_setprio(1);                                     \
  _Pragma("unroll")                                                  \
  for (int mf = 0; mf < 4; ++mf)                                     \
    _Pragma("unroll")                                                \
    for (int nf = 0; nf < FN; ++nf)                                  \
      acc[(M0) + mf][nf] = __builtin_amdgcn_mfma_f32_16x16x32_bf16(  \
          a_[(M0) + mf], b_[nf][KX], acc[(M0) + mf][nf], 0, 0, 0);   \
  __builtin_amdgcn_s_setprio(0);

  const int nit = Kloop >> 7;

  stA(0, 0, 0); stA(0, 1, 0);
  stB(0, 0, 0); if (BH == 2) stB(0, 1, 0);
  stB(1, 0, 1); if (BH == 2) stB(1, 1, 1);
  stA(1, 0, 1);
  VMC_STEADY;
  hard_barrier();

  for (int i = 0; i < nit; ++i) {
    const int t1 = 2 * i + 1, t2 = 2 * i + 2, t3 = 2 * i + 3;
    const bool g2 = (i < nit - 1);
    // ---- P1 ----
    lda(0, 0); ldb(0);
    stA(1, 1, t1);
    hard_barrier(); LGKM0;
    MFMA_HALF(0, 0)
    hard_barrier();
    // ---- P2 ----
    if (g2) stB(0, 0, t2);
    hard_barrier();
    MFMA_HALF(4, 0)
    hard_barrier();
    // ---- P3 ----
    lda(0, 32);
    if (g2 && BH == 2) stB(0, 1, t2);
    hard_barrier(); LGKM0;
    MFMA_HALF(0, 1)
    hard_barrier();
    // ---- P4 ----
    if (g2) stA(0, 0, t2);
    if (i == nit - 1) { asm volatile("s_waitcnt vmcnt(0)" ::: "memory"); }
    else { VMC_STEADY; }
    hard_barrier();
    MFMA_HALF(4, 1)
    hard_barrier();
    // ---- P5 ----
    lda(1, 0); ldb(1);
    if (g2) stA(0, 1, t2);
    hard_barrier(); LGKM0;
    MFMA_HALF(0, 0)
    hard_barrier();
    // ---- P6 ----
    if (g2) stB(1, 0, t3);
    hard_barrier();
    MFMA_HALF(4, 0)
    hard_barrier();
    // ---- P7 ----
    lda(1, 32);
    if (g2 && BH == 2) stB(1, 1, t3);
    hard_barrier(); LGKM0;
    MFMA_HALF(0, 1)
    hard_barrier();
    // ---- P8 ----
    if (g2) {
      stA(1, 0, t3);
      VMC_STEADY;
    }
    hard_barrier();
    MFMA_HALF(4, 1)
    hard_barrier();
  }
#undef LGKM0
#undef VMC_STEADY
#undef MFMA_HALF
}

// ---------------- o-proj: FN=2, out = acc + bo + x (f32), restaged ----------
__global__ __launch_bounds__(512, 1)
void k_oproj(const bf16_t* __restrict__ A, const bf16_t* __restrict__ BT,
             const float* __restrict__ bias, const float* __restrict__ res,
             float* __restrict__ outF) {
  extern __shared__ __align__(16) bf16_t sh8[];
  const int nt = DIMSZ / 128;  // 16
  int bm = blockIdx.x / nt, bn = blockIdx.x % nt;   // natural mapping
  f32x4 acc[8][2] = {};
  gemm8_loop<2>(A, BT, DIMSZ, DIMSZ, bm, bn, acc, sh8);
  int tid = threadIdx.x, wave = tid >> 6, lane = tid & 63, lr = lane & 15, lg = lane >> 4;
  int wm = wave >> 2, wn = wave & 3;
  float* shF = (float*)sh8;
  int rl0 = wm * 128 + lg * 4;
  int cl0 = wn * 32 + lr;
#pragma unroll
  for (int nf = 0; nf < 2; ++nf) {
    int cl = cl0 + nf * 16;
    float bi = bias[bn * 128 + cl];
#pragma unroll
    for (int mf = 0; mf < 8; ++mf)
#pragma unroll
      for (int j = 0; j < 4; ++j)
        shF[(rl0 + mf * 16 + j) * 128 + cl] = acc[mf][nf][j] + bi;
  }
  hard_barrier();
  const float* rbase = res + (size_t)(bm * 256) * DIMSZ + bn * 128;
  float* gbase = outF + (size_t)(bm * 256) * DIMSZ + bn * 128;
#pragma unroll
  for (int s = 0; s < 16; ++s) {
    int flat = s * 512 + tid;
    int row = flat >> 5, cu = flat & 31;
    f32x4 v = *(const f32x4*)(shF + row * 128 + cu * 4);
    f32x4 r4 = *(const f32x4*)(rbase + (size_t)row * DIMSZ + cu * 4);
    *(f32x4*)(gbase + (size_t)row * DIMSZ + cu * 4) = v + r4;
  }
}

// ---------------- ffn1: FN=4, out = gelu(acc + b1) bf16, restaged -----------
__global__ __launch_bounds__(512, 1)
void k_ffn1(const bf16_t* __restrict__ A, const bf16_t* __restrict__ BT,
            const float* __restrict__ bias, bf16_t* __restrict__ outB) {
  extern __shared__ __align__(16) bf16_t sh8[];
  const int nt = FFDIM / 256;  // 32
  int bm = blockIdx.x / nt, bn = blockIdx.x % nt;   // natural mapping
  f32x4 acc[8][4] = {};
  gemm8_loop<4>(A, BT, DIMSZ, DIMSZ, bm, bn, acc, sh8);
  int tid = threadIdx.x, wave = tid >> 6, lane = tid & 63, lr = lane & 15, lg = lane >> 4;
  int wm = wave >> 2, wn = wave & 3;
  int rl0 = wm * 128 + lg * 4;
  int cl0 = wn * 64 + lr;
#pragma unroll
  for (int nf = 0; nf < 4; ++nf) {
    int cl = cl0 + nf * 16;
    float bi = bias[bn * 256 + cl];
#pragma unroll
    for (int mf = 0; mf < 8; ++mf)
#pragma unroll
      for (int j = 0; j < 4; ++j)
        sh8[(rl0 + mf * 16 + j) * 256 + cl] = (bf16_t)gelu_f(acc[mf][nf][j] + bi);
  }
  hard_barrier();
  bf16_t* gbase = outB + (size_t)(bm * 256) * FFDIM + bn * 256;
#pragma unroll
  for (int s = 0; s < 16; ++s) {
    int flat = s * 512 + tid;
    int row = flat >> 5, cu = flat & 31;
    f32x4 v = *(const f32x4*)(sh8 + row * 256 + cu * 8);
    *(f32x4*)(gbase + (size_t)row * FFDIM + cu * 8) = v;
  }
}

// ---------------- ffn2: FN=4 split-K x2 -> f16 partials (coalesced) ---------
// Keeps the chunked mapping (r8): per-XCD 2D regions gave ideal FETCH.
// No atomics: kh-half writes pure-GEMM partial (no bias) to p0/p1 as f16.
__global__ __launch_bounds__(512, 1)
void k_ffn2(const bf16_t* __restrict__ A, const bf16_t* __restrict__ BT,
            f16_t* __restrict__ p0, f16_t* __restrict__ p1) {
  extern __shared__ __align__(16) bf16_t sh8[];
  int swz = (blockIdx.x & 7) * 32 + (blockIdx.x >> 3);
  int kh = swz >> 7;
  int tile = swz & 127;
  int bm = tile >> 3, bn = tile & 7;   // 16 x 8
  f32x4 acc[8][4] = {};
  gemm8_loop<4>(A + kh * (FFDIM / 2), BT + kh * (FFDIM / 2), FFDIM, FFDIM / 2,
                bm, bn, acc, sh8);
  int tid = threadIdx.x, wave = tid >> 6, lane = tid & 63, lr = lane & 15, lg = lane >> 4;
  int wm = wave >> 2, wn = wave & 3;
  // phase A: acc -> LDS f16 [256][256] (128 KB)
  f16_t* shH = (f16_t*)sh8;
  int rl0 = wm * 128 + lg * 4;
  int cl0 = wn * 64 + lr;
#pragma unroll
  for (int nf = 0; nf < 4; ++nf) {
    int cl = cl0 + nf * 16;
#pragma unroll
    for (int mf = 0; mf < 8; ++mf)
#pragma unroll
      for (int j = 0; j < 4; ++j)
        shH[(rl0 + mf * 16 + j) * 256 + cl] = (f16_t)acc[mf][nf][j];
  }
  hard_barrier();
  // phase B: coalesced LDS -> partial
  f16_t* gbase = (kh ? p1 : p0) + (size_t)(bm * 256) * DIMSZ + bn * 256;
#pragma unroll
  for (int s = 0; s < 16; ++s) {
    int flat = s * 512 + tid;
    int row = flat >> 5, cu = flat & 31;   // 32 x (8 f16 = 16B) per 256-col row
    f32x4 v = *(const f32x4*)(shH + row * 256 + cu * 8);
    *(f32x4*)(gbase + (size_t)row * DIMSZ + cu * 8) = v;
  }
}

// ---------------- ffn2 reduce: outx = x1(outx) + p0 + p1 + b2 ----------------
__global__ __launch_bounds__(256)
void k_ffn2red(const f16_t* __restrict__ p0, const f16_t* __restrict__ p1,
               const float* __restrict__ b2, float* __restrict__ outx) {
  int row = blockIdx.x;
  int c0 = threadIdx.x * 8;
  size_t base = (size_t)row * DIMSZ + c0;
  f16x8 a = *(const f16x8*)(p0 + base);
  f16x8 b = *(const f16x8*)(p1 + base);
  f32x4 o0 = *(const f32x4*)(outx + base);
  f32x4 o1 = *(const f32x4*)(outx + base + 4);
  f32x4 b0 = *(const f32x4*)(b2 + c0);
  f32x4 b1 = *(const f32x4*)(b2 + c0 + 4);
#pragma unroll
  for (int i = 0; i < 4; ++i) {
    o0[i] += (float)a[i] + (float)b[i] + b0[i];
    o1[i] += (float)a[4 + i] + (float)b[4 + i] + b1[i];
  }
  *(f32x4*)(outx + base) = o0;
  *(f32x4*)(outx + base + 4) = o1;
}

// ---------------- fused QKV: N = 2304 (2048 q | 128 k | 128 v), restaged ----
__global__ __launch_bounds__(512, 1)
void k_qkv(const bf16_t* __restrict__ A, const bf16_t* __restrict__ BT,
           const float* __restrict__ bq, const float* __restrict__ bk,
           const float* __restrict__ bv,
           bf16_t* __restrict__ qb, float* __restrict__ outk,
           float* __restrict__ outv, bf16_t* __restrict__ kbf,
           bf16_t* __restrict__ vbf) {
  extern __shared__ __align__(16) bf16_t sh8[];
  const int nt = NQKV / 256;  // 9
  int bm = blockIdx.x / nt, bn = blockIdx.x % nt;   // natural mapping
  f32x4 acc[8][4] = {};
  gemm8_loop<4>(A, BT, DIMSZ, DIMSZ, bm, bn, acc, sh8);
  int tid = threadIdx.x, wave = tid >> 6, lane = tid & 63, lr = lane & 15, lg = lane >> 4;
  int wm = wave >> 2, wn = wave & 3;
  int rl0 = wm * 128 + lg * 4;
  int cl0 = wn * 64 + lr;
#pragma unroll
  for (int nf = 0; nf < 4; ++nf) {
    int cl = cl0 + nf * 16;
    int cg = bn * 256 + cl;
    float bi = (cg < 2048) ? bq[cg] : (cg < 2176 ? bk[cg - 2048] : bv[cg - 2176]);
#pragma unroll
    for (int mf = 0; mf < 8; ++mf)
#pragma unroll
      for (int j = 0; j < 4; ++j) {
        float v = acc[mf][nf][j] + bi;
        sh8[(rl0 + mf * 16 + j) * 256 + cl] = (bf16_t)v;
        if (cg >= 2048) {
          int r = bm * 256 + rl0 + mf * 16 + j;
          if (cg < 2176) outk[(size_t)r * HD + (cg - 2048)] = v;
          else           outv[(size_t)r * HD + (cg - 2176)] = v;
        }
      }
  }
  hard_barrier();
#pragma unroll
  for (int s = 0; s < 16; ++s) {
    int flat = s * 512 + tid;
    int row = flat >> 5, cu = flat & 31;
    f32x4 v = *(const f32x4*)(sh8 + row * 256 + cu * 8);
    int r = bm * 256 + row;
    if (bn < 8) {
      *(f32x4*)(qb + (size_t)r * DIMSZ + bn * 256 + cu * 8) = v;
    } else {
      int ce = cu * 8;  // 0..255
      if (ce < 128) *(f32x4*)(kbf + (size_t)r * HD + ce) = v;
      else          *(f32x4*)(vbf + (size_t)r * HD + (ce - 128)) = v;
    }
  }
}

// ---------------- causal flash attention (MQA) ----------------
__global__ __launch_bounds__(256, 2)
void k_attn(const bf16_t* __restrict__ q, const bf16_t* __restrict__ k,
            const bf16_t* __restrict__ vt, bf16_t* __restrict__ ctx) {
  __shared__ __align__(16) bf16_t Ks[2][64 * 128];
  __shared__ __align__(16) bf16_t Vs[2][128 * 64];
  __shared__ bf16_t Pw[4][16][72];
  int pp = blockIdx.x, h = blockIdx.y, b = blockIdx.z;
  int tid = threadIdx.x, wave = tid >> 6, lane = tid & 63, lr = lane & 15, lg = lane >> 4;
  const bf16_t* kb = k + (size_t)b * SEQ * HD;
  const bf16_t* vb = vt + (size_t)b * HD * SEQ;

#define STAGE_TILE(buf, s0_)                                                      \
  {                                                                               \
    _Pragma("unroll")                                                             \
    for (int i = 0; i < 4; ++i) {                                                 \
      int flat = (i * 256 + tid) * 8;                                             \
      int kr = flat >> 7, kc = flat & 127;                                        \
      int ksrc = (((kc >> 3) ^ (kr & 7)) << 3) | (kc & 7);                        \
      async16(kb + (size_t)((s0_) + kr) * HD + ksrc, (void*)(Ks[buf] + flat));    \
      int vr = flat >> 6, vc = flat & 63;                                         \
      int vsrc = (((vc >> 3) ^ (vr & 7)) << 3) | (vc & 7);                        \
      async16(vb + (size_t)vr * SEQ + (s0_) + vsrc, (void*)(Vs[buf] + flat));     \
    }                                                                             \
  }

  for (int half = 0; half < 2; ++half) {
    int qt = half ? (31 - pp) : pp;
    int q0 = qt * 64;
    int qw = q0 + wave * 16;
    const bf16_t* qbase = q + ((size_t)(b * SEQ + qw + lr)) * DIMSZ + h * HD;
    bf16x8 qf[4];
#pragma unroll
    for (int kk = 0; kk < 4; ++kk) qf[kk] = *(const bf16x8*)(qbase + kk * 32 + lg * 8);
    f32x4 o[8] = {};
    float m_[4], l_[4];
#pragma unroll
    for (int j = 0; j < 4; ++j) { m_[j] = -3.0e38f; l_[j] = 0.f; }
    int qglob0 = qw + lg * 4;
    int ntiles = qt + 1;

    STAGE_TILE(0, 0)
    __syncthreads();
    for (int t = 0; t < ntiles; ++t) {
      int cur = t & 1;
      if (t + 1 < ntiles) STAGE_TILE(cur ^ 1, (t + 1) * 64)
      int s0 = t * 64;
      const bf16_t* Kc = Ks[cur];
      const bf16_t* Vc = Vs[cur];
      f32x4 sf[4] = {};
#pragma unroll
      for (int nf = 0; nf < 4; ++nf) {
        int R = nf * 16 + lr;
#pragma unroll
        for (int kk = 0; kk < 4; ++kk)
          sf[nf] = __builtin_amdgcn_mfma_f32_16x16x32_bf16(
              qf[kk],
              *(const bf16x8*)(Kc + R * 128 + (((kk * 4 + lg) ^ (R & 7)) << 3)),
              sf[nf], 0, 0, 0);
      }
#pragma unroll
      for (int nf = 0; nf < 4; ++nf) {
        int col = s0 + nf * 16 + lr;
#pragma unroll
        for (int j = 0; j < 4; ++j) {
          float v = sf[nf][j] * 0.088388347648318447f;
          sf[nf][j] = (col <= qglob0 + j) ? v : -3.0e38f;
        }
      }
      float mx[4];
#pragma unroll
      for (int j = 0; j < 4; ++j)
        mx[j] = fmaxf(fmaxf(sf[0][j], sf[1][j]), fmaxf(sf[2][j], sf[3][j]));
#pragma unroll
      for (int o_ = 1; o_ < 16; o_ <<= 1)
#pragma unroll
        for (int j = 0; j < 4; ++j) mx[j] = fmaxf(mx[j], __shfl_xor(mx[j], o_));
      float fsc[4], mn[4];
#pragma unroll
      for (int j = 0; j < 4; ++j) {
        mn[j] = fmaxf(m_[j], mx[j]);
        fsc[j] = __expf(m_[j] - mn[j]);
        m_[j] = mn[j];
      }
      float ps[4] = {0.f, 0.f, 0.f, 0.f};
#pragma unroll
      for (int nf = 0; nf < 4; ++nf)
#pragma unroll
        for (int j = 0; j < 4; ++j) {
          float pv = __expf(sf[nf][j] - mn[j]);
          ps[j] += pv;
          Pw[wave][lg * 4 + j][nf * 16 + lr] = (bf16_t)pv;
        }
#pragma unroll
      for (int o_ = 1; o_ < 16; o_ <<= 1)
#pragma unroll
        for (int j = 0; j < 4; ++j) ps[j] += __shfl_xor(ps[j], o_);
#pragma unroll
      for (int j = 0; j < 4; ++j) l_[j] = l_[j] * fsc[j] + ps[j];
#pragma unroll
      for (int df = 0; df < 8; ++df)
#pragma unroll
        for (int j = 0; j < 4; ++j) o[df][j] *= fsc[j];
      asm volatile("" ::: "memory");
      bf16x8 pa[2];
#pragma unroll
      for (int kk = 0; kk < 2; ++kk)
        pa[kk] = *(const bf16x8*)(&Pw[wave][lr][kk * 32 + lg * 8]);
#pragma unroll
      for (int df = 0; df < 8; ++df) {
        int R = df * 16 + lr;
#pragma unroll
        for (int kk = 0; kk < 2; ++kk)
          o[df] = __builtin_amdgcn_mfma_f32_16x16x32_bf16(
              pa[kk],
              *(const bf16x8*)(Vc + R * 64 + (((kk * 4 + lg) ^ (R & 7)) << 3)),
              o[df], 0, 0, 0);
      }
      __syncthreads();
    }
    bf16_t* cb = ctx + ((size_t)(b * SEQ + qw)) * DIMSZ + h * HD;
#pragma unroll
    for (int df = 0; df < 8; ++df)
#pragma unroll
      for (int j = 0; j < 4; ++j)
        cb[(size_t)(lg * 4 + j) * DIMSZ + df * 16 + lr] = (bf16_t)(o[df][j] / l_[j]);
  }
#undef STAGE_TILE
}

extern "C" void kernel_launch(void* const* d_in, const int* in_sizes, int n_in,
                              void* d_out, int out_size, void* d_ws, size_t ws_size,
                              hipStream_t stream) {
  const float* x   = (const float*)d_in[0];
  const float* wq  = (const float*)d_in[2];
  const float* bq  = (const float*)d_in[3];
  const float* wk  = (const float*)d_in[4];
  const float* bk  = (const float*)d_in[5];
  const float* wv  = (const float*)d_in[6];
  const float* bv  = (const float*)d_in[7];
  const float* wo  = (const float*)d_in[8];
  const float* bo  = (const float*)d_in[9];
  const float* g1  = (const float*)d_in[10];
  const float* be1 = (const float*)d_in[11];
  const float* g2  = (const float*)d_in[12];
  const float* be2 = (const float*)d_in[13];
  const float* w1  = (const float*)d_in[14];
  const float* bb1 = (const float*)d_in[15];
  const float* w2  = (const float*)d_in[16];
  const float* bb2 = (const float*)d_in[17];

  float* outx = (float*)d_out;                       // [4096][2048] (also x1 scratch)
  float* outk = outx + (size_t)MROWS * DIMSZ;        // [4096][128]
  float* outv = outk + (size_t)MROWS * HD;           // [4096][128]

  char* p = (char*)d_ws;
  auto alloc = [&](size_t bytes) -> char* {
    char* r = p;
    p += (bytes + 255) & ~(size_t)255;
    return r;
  };
  bf16_t* wqkvT = (bf16_t*)alloc((size_t)NQKV * DIMSZ * 2);   // [2304][2048]
  bf16_t* woT = (bf16_t*)alloc((size_t)DIMSZ * DIMSZ * 2);
  bf16_t* w1T = (bf16_t*)alloc((size_t)FFDIM * DIMSZ * 2);
  bf16_t* w2T = (bf16_t*)alloc((size_t)DIMSZ * FFDIM * 2);
  bf16_t* hb  = (bf16_t*)alloc((size_t)MROWS * DIMSZ * 2);  // h, later ctx
  bf16_t* qb  = (bf16_t*)alloc((size_t)MROWS * DIMSZ * 2);  // q, later h2
  bf16_t* kbf = (bf16_t*)alloc((size_t)MROWS * HD * 2);
  bf16_t* vbf = (bf16_t*)alloc((size_t)MROWS * HD * 2);
  bf16_t* vtb = (bf16_t*)alloc((size_t)BATCH * HD * SEQ * 2);
  bf16_t* f1b = (bf16_t*)alloc((size_t)MROWS * FFDIM * 2);
  f16_t* p0  = (f16_t*)alloc((size_t)MROWS * DIMSZ * 2);    // ffn2 partial kh=0
  f16_t* p1  = (f16_t*)alloc((size_t)MROWS * DIMSZ * 2);    // ffn2 partial kh=1
  (void)ws_size; (void)in_sizes; (void)n_in; (void)out_size;

  dim3 blk(256);
  const int LDSG = 131072;  // all gemm kernels: 128 KiB dynamic
  // all weight transposes in one launch (10368 tiles)
  k_trall<<<10368, blk, 0, stream>>>(wq, wk, wv, wo, w1, w2, wqkvT, woT, w1T, w2T);
  // ln1: x -> h(bf16)
  k_layernorm<<<MROWS, blk, 0, stream>>>(x, g1, be1, hb);
  // fused q,k,v projection (144 blocks)
  k_qkv<<<(MROWS / 256) * (NQKV / 256), 512, LDSG, stream>>>(
      hb, wqkvT, bq, bk, bv, qb, outk, outv, kbf, vbf);
  k_transpose_v<<<dim3(SEQ / 32, HD / 32, BATCH), blk, 0, stream>>>(vbf, vtb);
  // attention -> ctx (reuse hb)
  k_attn<<<dim3(SEQ / 64 / 2, NH, BATCH), blk, 0, stream>>>(qb, kbf, vtb, hb);
  // o-proj + residual -> outx (x1): 256 blocks
  k_oproj<<<(MROWS / 256) * (DIMSZ / 128), 512, LDSG, stream>>>(hb, woT, bo, x, outx);
  // ln2: x1 -> h2 (reuse qb)
  k_layernorm<<<MROWS, blk, 0, stream>>>(outx, g2, be2, qb);
  // ffn1 + exact gelu -> f1b (bf16): 512 blocks
  k_ffn1<<<(MROWS / 256) * (FFDIM / 256), 512, LDSG, stream>>>(qb, w1T, bb1, f1b);
  // ffn2 split-K x2 -> f16 partials (256 blocks), then reduce into outx
  k_ffn2<<<256, 512, LDSG, stream>>>(f1b, w2T, p0, p1);
  k_ffn2red<<<MROWS, blk, 0, stream>>>(p0, p1, bb2, outx);
}